// Round 1
// baseline (1397.010 us; speedup 1.0000x reference)
//
#include <hip/hip_runtime.h>
#include <math.h>

namespace {

constexpr int BATCH = 2;
constexpr int LSEQ  = 8000;
constexpr int MROWS = BATCH * LSEQ;   // 16000
constexpr int EC    = 192;
constexpr int NC_   = 16;
constexpr int NCH   = 40;             // chunks per sequence
constexpr int CHL   = 200;            // chunk length (40*200 = 8000)
constexpr int BLEc  = MROWS * EC;     // 3,072,000
constexpr int BL38c = MROWS * 38;     // 608,000

__device__ __forceinline__ float siluf(float x) { return x / (1.f + __expf(-x)); }
__device__ __forceinline__ float softplusf(float x) {
  if (x > 20.f) return x;
  return log1pf(__expf(x));
}

// ---------------- Stage A: downsample conv3d (stride2, k2, valid) + bias ----
// x: (2,48,40,40,40)  w: (96,48,2,2,2)  out: (2,96,8000) with l=(d*20+h)*20+w
__global__ void ds_conv_kernel(const float* __restrict__ x, const float* __restrict__ w,
                               const float* __restrict__ bias, float* __restrict__ out) {
  int idx = blockIdx.x * 256 + threadIdx.x;       // 2*96*8000 = 1,536,000
  if (idx >= 2 * 96 * 8000) return;
  int l  = idx % 8000;
  int oc = (idx / 8000) % 96;
  int b  = idx / (8000 * 96);
  int wd = l % 20, hh = (l / 20) % 20, dd = l / 400;
  const float* xb = x + (size_t)b * 48 * 64000 + (2*dd)*1600 + (2*hh)*40 + 2*wd;
  const float* wr = w + oc * 48 * 8;
  float acc = bias[oc];
  #pragma unroll 8
  for (int c = 0; c < 48; ++c) {
    const float* xp = xb + c * 64000;
    const float* wc = wr + c * 8;
    acc += xp[0]*wc[0] + xp[1]*wc[1] + xp[40]*wc[2] + xp[41]*wc[3]
         + xp[1600]*wc[4] + xp[1601]*wc[5] + xp[1640]*wc[6] + xp[1641]*wc[7];
  }
  out[idx] = acc;
}

// ---------------- channel-first LN over 96 channels + transpose to (b,l,96) --
__global__ void ln_chan_kernel(const float* __restrict__ tin, const float* __restrict__ w,
                               const float* __restrict__ bv, float* __restrict__ xf) {
  int idx = blockIdx.x * 256 + threadIdx.x;   // 16000 locations
  if (idx >= MROWS) return;
  int b = idx / LSEQ, l = idx % LSEQ;
  const float* base = tin + (size_t)b * 96 * LSEQ + l;
  float s = 0.f, s2 = 0.f;
  for (int c = 0; c < 96; ++c) { float v = base[(size_t)c * LSEQ]; s += v; s2 += v * v; }
  float m = s * (1.f/96.f);
  float var = s2 * (1.f/96.f) - m * m;
  float rs = rsqrtf(var + 1e-6f);
  float* orow = xf + (size_t)idx * 96;
  for (int c = 0; c < 96; ++c) {
    float v = base[(size_t)c * LSEQ];
    orow[c] = (v - m) * rs * w[c] + bv[c];
  }
}

// ---------------- row LN over last dim 96 (wave per row) ---------------------
__global__ void ln_row_kernel(const float* __restrict__ in, const float* __restrict__ w,
                              const float* __restrict__ bv, float* __restrict__ out, float eps) {
  int lane = threadIdx.x & 63;
  int row = blockIdx.x * 4 + (threadIdx.x >> 6);   // 4000 blocks * 4 = 16000
  const float* r = in + (size_t)row * 96;
  float v0 = r[lane];
  float v1 = (lane < 32) ? r[64 + lane] : 0.f;
  float s = v0 + v1, s2 = v0*v0 + v1*v1;
  #pragma unroll
  for (int o = 32; o; o >>= 1) { s += __shfl_xor(s, o); s2 += __shfl_xor(s2, o); }
  float m = s * (1.f/96.f);
  float var = s2 * (1.f/96.f) - m * m;
  float rs = rsqrtf(var + eps);
  float* orow = out + (size_t)row * 96;
  orow[lane] = (v0 - m) * rs * w[lane] + bv[lane];
  if (lane < 32) orow[64 + lane] = (v1 - m) * rs * w[64 + lane] + bv[64 + lane];
}

// ---------------- generic tiled fp32 GEMM: C[m,n] = act(sum_k A[m,k]W[n,k]+bias) ----
// ACT: 0 none, 1 exact gelu.  OUTM: 0 row-major (ldc=Nn), 1 scatter (b,n,l) for fc2.
template<int ACT, int OUTM, bool TWOA>
__global__ __launch_bounds__(256) void gemm_k(const float* __restrict__ A, const float* __restrict__ A2,
                      const float* __restrict__ W, const float* __restrict__ bias,
                      float* __restrict__ Cmat, int M, int Nn, int Kk) {
  __shared__ float As[64][33];
  __shared__ float Ws[64][33];
  int tid = threadIdx.x;
  int bm = blockIdx.x, bn = blockIdx.y;
  int ty = tid >> 4, tx = tid & 15;
  float acc[4][4] = {};
  for (int k0 = 0; k0 < Kk; k0 += 32) {
    for (int i = tid; i < 64 * 32; i += 256) {
      int r = i >> 5, cc = i & 31;
      int m = bm * 64 + r;
      float va = 0.f;
      if (m < M) {
        va = A[(size_t)m * Kk + k0 + cc];
        if (TWOA) va += A2[(size_t)m * Kk + k0 + cc];
      }
      As[r][cc] = va;
      int n = bn * 64 + r;
      Ws[r][cc] = (n < Nn) ? W[(size_t)n * Kk + k0 + cc] : 0.f;
    }
    __syncthreads();
    #pragma unroll
    for (int k = 0; k < 32; ++k) {
      float av[4], wv[4];
      #pragma unroll
      for (int i = 0; i < 4; ++i) av[i] = As[ty*4+i][k];
      #pragma unroll
      for (int j = 0; j < 4; ++j) wv[j] = Ws[tx*4+j][k];
      #pragma unroll
      for (int i = 0; i < 4; ++i)
        #pragma unroll
        for (int j = 0; j < 4; ++j) acc[i][j] += av[i] * wv[j];
    }
    __syncthreads();
  }
  #pragma unroll
  for (int i = 0; i < 4; ++i) {
    int m = bm * 64 + ty * 4 + i;
    if (m >= M) continue;
    #pragma unroll
    for (int j = 0; j < 4; ++j) {
      int n = bn * 64 + tx * 4 + j;
      if (n >= Nn) continue;
      float v = acc[i][j] + (bias ? bias[n] : 0.f);
      if (ACT == 1) v = 0.5f * v * (1.f + erff(v * 0.70710678118f));
      if (OUTM == 0) Cmat[(size_t)m * Nn + n] = v;
      else {
        int b = m / LSEQ, l = m % LSEQ;
        Cmat[((size_t)(b * 96 + n)) * LSEQ + l] = v;
      }
    }
  }
}

// ---------------- causal depthwise conv1d (K=4) + silu, with direction ------
// xz: (b,l,384); xi = first 192 cols. out xc[dir]: (b, s(processed), 192)
__global__ void conv1d_kernel(const float* __restrict__ xz, const float* __restrict__ cw,
                              const float* __restrict__ cb, float* __restrict__ xc) {
  int dir = blockIdx.y;
  int idx = blockIdx.x * 256 + threadIdx.x;   // 16000*192
  int e = idx % EC;
  int m = idx / EC;
  int b = m / LSEQ, s = m % LSEQ;
  const float* w = cw + dir * EC * 4 + e * 4;
  float acc = cb[dir * EC + e];
  #pragma unroll
  for (int k = 0; k < 4; ++k) {
    int sp = s - 3 + k;
    if (sp >= 0) {
      int p = dir ? (LSEQ - 1 - sp) : sp;
      acc += w[k] * xz[((size_t)(b * LSEQ + p)) * 384 + e];
    }
  }
  xc[(size_t)dir * BLEc + (size_t)m * EC + e] = siluf(acc);
}

// ---------------- x-proj: dbl[m, r38] = sum_e xc[m,e] * xp_w[r38,e] ----------
__global__ void gemm_xp_kernel(const float* __restrict__ xc, const float* __restrict__ xp_w,
                               float* __restrict__ dbl) {
  int dir = blockIdx.y;
  int idx = blockIdx.x * 256 + threadIdx.x;   // 16000*38 = 608000
  int r = idx % 38;
  int m = idx / 38;
  const float* wv = xp_w + dir * 38 * EC + r * EC;
  const float* xv = xc + (size_t)dir * BLEc + (size_t)m * EC;
  float acc = 0.f;
  #pragma unroll 8
  for (int e = 0; e < EC; ++e) acc += xv[e] * wv[e];
  dbl[(size_t)dir * BL38c + (size_t)m * 38 + r] = acc;
}

// ---------------- dt = softplus(dbl[:,:6] @ dtw^T + dtb) ---------------------
__global__ void dt_kernel(const float* __restrict__ dbl, const float* __restrict__ dtw,
                          const float* __restrict__ dtb, float* __restrict__ dt) {
  int dir = blockIdx.y;
  int idx = blockIdx.x * 256 + threadIdx.x;   // 16000*192
  int e = idx % EC;
  int m = idx / EC;
  const float* db = dbl + (size_t)dir * BL38c + (size_t)m * 38;
  const float* wr = dtw + dir * EC * 6 + e * 6;
  float acc = dtb[dir * EC + e];
  #pragma unroll
  for (int r = 0; r < 6; ++r) acc += db[r] * wr[r];
  dt[(size_t)dir * BLEc + (size_t)m * EC + e] = softplusf(acc);
}

// ---------------- chunked selective scan -------------------------------------
// pass1: per (dir,b,chunk,e,n): local scan over CHL steps assuming h_in=0;
//        emit P=prod(a), hend.
__global__ void scan_pass1(const float* __restrict__ dt, const float* __restrict__ xc,
                           const float* __restrict__ dbl, const float* __restrict__ A_log,
                           float* __restrict__ Pm, float* __restrict__ hend) {
  int idx = blockIdx.x * 256 + threadIdx.x;   // 2*2*40*192*16 = 491,520
  int n = idx & 15;
  int t = idx >> 4;
  int e = t % EC; t /= EC;
  int c = t % NCH; t /= NCH;
  int b = t & 1;  int dir = t >> 1;
  const float* dtp  = dt  + (size_t)dir * BLEc;
  const float* xcp  = xc  + (size_t)dir * BLEc;
  const float* dblp = dbl + (size_t)dir * BL38c;
  float A = -__expf(A_log[dir * EC * NC_ + e * NC_ + n]);
  float P = 1.f, h = 0.f;
  int base_s = c * CHL;
  for (int s = 0; s < CHL; ++s) {
    size_t row = (size_t)(b * LSEQ + base_s + s);
    float dtv = dtp[row * EC + e];
    float xcv = xcp[row * EC + e];
    float Bv  = dblp[row * 38 + 6 + n];
    float a = __expf(dtv * A);
    P *= a;
    h = h * a + dtv * Bv * xcv;
  }
  int pidx = (((dir * 2 + b) * EC + e) * NC_ + n) * NCH + c;
  Pm[pidx] = P;
  hend[pidx] = h;
}

// pass2: per (dir,b,e,n): scan over NCH chunk summaries, emit carry-in per chunk.
__global__ void scan_pass2(const float* __restrict__ Pm, const float* __restrict__ hend,
                           float* __restrict__ carry) {
  int idx = blockIdx.x * 256 + threadIdx.x;   // 2*2*192*16 = 12288
  if (idx >= 2 * 2 * EC * NC_) return;
  size_t base = (size_t)idx * NCH;
  float H = 0.f;
  for (int c = 0; c < NCH; ++c) {
    carry[base + c] = H;
    H = H * Pm[base + c] + hend[base + c];
  }
}

// pass3: per (dir,b,chunk,e) group of 16 lanes (n): recompute with carry-in,
//        y = sum_n C*h + xc*D, gate with silu(z at original pos), write un-reversed.
__global__ void scan_pass3(const float* __restrict__ dt, const float* __restrict__ xc,
                           const float* __restrict__ dbl, const float* __restrict__ carry,
                           const float* __restrict__ A_log, const float* __restrict__ Dp,
                           const float* __restrict__ xz, float* __restrict__ ybuf) {
  int tid = threadIdx.x;
  int lane_n = tid & 15;
  int g = blockIdx.x * 16 + (tid >> 4);   // groups: 2*2*40*192 = 30,720
  int e = g % EC; g /= EC;
  int c = g % NCH; g /= NCH;
  int b = g & 1;  int dir = g >> 1;
  const float* dtp  = dt  + (size_t)dir * BLEc;
  const float* xcp  = xc  + (size_t)dir * BLEc;
  const float* dblp = dbl + (size_t)dir * BL38c;
  float A = -__expf(A_log[dir * EC * NC_ + e * NC_ + lane_n]);
  float Dv = Dp[dir * EC + e];
  float h = carry[(size_t)((((dir * 2 + b) * EC + e) * NC_ + lane_n)) * NCH + c];
  for (int s0 = 0; s0 < CHL; ++s0) {
    int gs = c * CHL + s0;
    size_t row = (size_t)(b * LSEQ + gs);
    float dtv = dtp[row * EC + e];
    float xcv = xcp[row * EC + e];
    float Bv = dblp[row * 38 + 6 + lane_n];
    float Cv = dblp[row * 38 + 22 + lane_n];
    float a = __expf(dtv * A);
    h = h * a + dtv * Bv * xcv;
    float part = h * Cv;
    part += __shfl_xor(part, 1);
    part += __shfl_xor(part, 2);
    part += __shfl_xor(part, 4);
    part += __shfl_xor(part, 8);
    if (lane_n == 0) {
      int p = dir ? (LSEQ - 1 - gs) : gs;
      size_t prow = (size_t)(b * LSEQ + p);
      float zv = xz[prow * 384 + 192 + e];
      ybuf[(size_t)dir * BLEc + prow * EC + e] = (part + xcv * Dv) * siluf(zv);
    }
  }
}

}  // namespace

extern "C" void kernel_launch(void* const* d_in, const int* in_sizes, int n_in,
                              void* d_out, int out_size, void* d_ws, size_t ws_size,
                              hipStream_t stream) {
  const float* x      = (const float*)d_in[0];
  const float* ds_w   = (const float*)d_in[1];
  const float* ds_b   = (const float*)d_in[2];
  const float* ds_ln_w= (const float*)d_in[3];
  const float* ds_ln_b= (const float*)d_in[4];
  const float* ln_w   = (const float*)d_in[5];
  const float* ln_b   = (const float*)d_in[6];
  const float* in_w   = (const float*)d_in[7];
  const float* conv_w = (const float*)d_in[8];
  const float* conv_b = (const float*)d_in[9];
  const float* xp_w   = (const float*)d_in[10];
  const float* dtp_w  = (const float*)d_in[11];
  const float* dtp_b  = (const float*)d_in[12];
  const float* A_log  = (const float*)d_in[13];
  const float* Dp     = (const float*)d_in[14];
  const float* out_w  = (const float*)d_in[15];
  const float* f_ln_w = (const float*)d_in[16];
  const float* f_ln_b = (const float*)d_in[17];
  const float* fc1_w  = (const float*)d_in[18];
  const float* fc1_b  = (const float*)d_in[19];
  const float* fc2_w  = (const float*)d_in[20];
  const float* fc2_b  = (const float*)d_in[21];
  float* outp = (float*)d_out;
  float* ws = (float*)d_ws;

  size_t o = 0;
  float* t_ds  = ws + o;  o += 1536000;
  float* xf    = ws + o;  o += 1536000;
  float* xn    = ws + o;  o += 1536000;
  float* xz    = ws + o;  o += 6144000;
  float* xcb   = ws + o;  o += 2 * (size_t)BLEc;
  float* dblb  = ws + o;  o += 2 * (size_t)BL38c;
  float* dtbuf = ws + o;  o += 2 * (size_t)BLEc;
  float* ybuf  = ws + o;  o += 2 * (size_t)BLEc;
  float* Pm    = ws + o;  o += 491520;
  float* hendb = ws + o;  o += 491520;
  float* carry = ws + o;  o += 491520;

  ds_conv_kernel<<<6000, 256, 0, stream>>>(x, ds_w, ds_b, t_ds);
  ln_chan_kernel<<<63, 256, 0, stream>>>(t_ds, ds_ln_w, ds_ln_b, xf);

  for (int i = 0; i < 2; ++i) {
    ln_row_kernel<<<4000, 256, 0, stream>>>(xf, ln_w + i * 96, ln_b + i * 96, xn, 1e-5f);
    gemm_k<0, 0, false><<<dim3(250, 6), 256, 0, stream>>>(
        xn, nullptr, in_w + (size_t)i * 384 * 96, nullptr, xz, MROWS, 384, 96);
    conv1d_kernel<<<dim3(12000, 2), 256, 0, stream>>>(
        xz, conv_w + (size_t)i * 2 * EC * 4, conv_b + (size_t)i * 2 * EC, xcb);
    gemm_xp_kernel<<<dim3(2375, 2), 256, 0, stream>>>(
        xcb, xp_w + (size_t)i * 2 * 38 * EC, dblb);
    dt_kernel<<<dim3(12000, 2), 256, 0, stream>>>(
        dblb, dtp_w + (size_t)i * 2 * EC * 6, dtp_b + (size_t)i * 2 * EC, dtbuf);
    scan_pass1<<<1920, 256, 0, stream>>>(
        dtbuf, xcb, dblb, A_log + (size_t)i * 2 * EC * NC_, Pm, hendb);
    scan_pass2<<<48, 256, 0, stream>>>(Pm, hendb, carry);
    scan_pass3<<<1920, 256, 0, stream>>>(
        dtbuf, xcb, dblb, carry, A_log + (size_t)i * 2 * EC * NC_,
        Dp + (size_t)i * 2 * EC, xz, ybuf);
    gemm_k<0, 0, true><<<dim3(250, 2), 256, 0, stream>>>(
        ybuf, ybuf + BLEc, out_w + (size_t)i * 96 * EC, nullptr, xf, MROWS, 96, EC);
  }

  ln_row_kernel<<<4000, 256, 0, stream>>>(xf, f_ln_w, f_ln_b, xn, 1e-6f);
  gemm_k<1, 0, false><<<dim3(250, 6), 256, 0, stream>>>(
      xn, nullptr, fc1_w, fc1_b, xz, MROWS, 384, 96);
  gemm_k<0, 1, false><<<dim3(250, 2), 256, 0, stream>>>(
      xz, nullptr, fc2_w, fc2_b, outp, MROWS, 96, 384);
}

// Round 2
// 695.224 us; speedup vs baseline: 2.0094x; 2.0094x over previous
//
#include <hip/hip_runtime.h>
#include <math.h>

namespace {

constexpr int BATCH = 2;
constexpr int LSEQ  = 8000;
constexpr int MROWS = BATCH * LSEQ;   // 16000
constexpr int EC    = 192;
constexpr int NC_   = 16;
constexpr int NCH   = 160;            // chunks per sequence
constexpr int CHL   = 50;             // chunk length (160*50 = 8000)
constexpr int BLEc  = MROWS * EC;     // 3,072,000
constexpr int BL38c = MROWS * 38;     // 608,000
constexpr int SUMW  = 2 * 2 * EC * NC_;  // 12288 chunk-summary width

__device__ __forceinline__ float siluf(float x) { return x / (1.f + __expf(-x)); }
__device__ __forceinline__ float softplusf(float x) {
  if (x > 20.f) return x;
  return log1pf(__expf(x));
}

// ---------------- row LN over last dim 96 (wave per row) ---------------------
__global__ void ln_row_kernel(const float* __restrict__ in, const float* __restrict__ w,
                              const float* __restrict__ bv, float* __restrict__ out, float eps) {
  int lane = threadIdx.x & 63;
  int row = blockIdx.x * 4 + (threadIdx.x >> 6);   // 4000 blocks * 4 = 16000
  const float* r = in + (size_t)row * 96;
  float v0 = r[lane];
  float v1 = (lane < 32) ? r[64 + lane] : 0.f;
  float s = v0 + v1, s2 = v0*v0 + v1*v1;
  #pragma unroll
  for (int o = 32; o; o >>= 1) { s += __shfl_xor(s, o); s2 += __shfl_xor(s2, o); }
  float m = s * (1.f/96.f);
  float var = s2 * (1.f/96.f) - m * m;
  float rs = rsqrtf(var + eps);
  float* orow = out + (size_t)row * 96;
  orow[lane] = (v0 - m) * rs * w[lane] + bv[lane];
  if (lane < 32) orow[64 + lane] = (v1 - m) * rs * w[64 + lane] + bv[64 + lane];
}

// ---------------- tiled fp32 GEMM: C[m,n] = act(sum_k A[m,k]W[n,k]+bias) -----
// Tile 128x64, BK=32, 256 threads, 8x4 acc/thread, K-transposed LDS (b128 frags).
// ACT: 0 none, 1 exact gelu.  OUTM: 0 row-major (ldc), 1 scatter (b,n,l).
// IM2COL: A-tile gathered from x (2,48,40,40,40) for the stride-2 k-2 ds-conv.
// M must be a multiple of 128 (16000 = 125*128 here); Kk multiple of 32.
template<int ACT, int OUTM, bool TWOA, bool IM2COL>
__global__ __launch_bounds__(256) void gemm_k(const float* __restrict__ A, const float* __restrict__ A2,
                      const float* __restrict__ W, const float* __restrict__ bias,
                      float* __restrict__ Cmat, int M, int Nn, int Kk, int ldc) {
  __shared__ float As[32][136];   // [k][r], row stride 544B (16B-aligned)
  __shared__ float Ws[32][68];    // [k][n]
  int tid = threadIdx.x;
  int bm = blockIdx.x, bn = blockIdx.y;
  int ty = tid >> 4, tx = tid & 15;   // ty: 8-row group, tx: 4-col group
  float acc[8][4] = {};
  for (int k0 = 0; k0 < Kk; k0 += 32) {
    // ---- stage A tile (128 x 32) ----
    if (IM2COL) {
      // col = c*8 + kd*4 + kh*2 + kw ; read float2 (kw pair) per slot
      #pragma unroll
      for (int i = tid; i < 128 * 16; i += 256) {
        int p  = i & 3;            // (kd,kh) pair
        int c4 = (i >> 2) & 3;     // channel within tile
        int r  = i >> 4;           // row 0..127
        int m = bm * 128 + r;
        int b = m / 8000, l = m % 8000;
        int dd = l / 400, hh = (l / 20) % 20, wd = l % 20;
        int off = (p >> 1) * 1600 + (p & 1) * 40;
        const float* xp = A + ((size_t)b * 48 + (k0 >> 3) + c4) * 64000
                            + dd * 3200 + hh * 80 + wd * 2 + off;
        float2 v = *(const float2*)xp;
        int k = c4 * 8 + p * 2;
        As[k][r] = v.x;
        As[k + 1][r] = v.y;
      }
    } else {
      #pragma unroll
      for (int i = tid; i < 128 * 8; i += 256) {
        int kq = i & 7, r = i >> 3;
        int m = bm * 128 + r;
        float4 va = *(const float4*)&A[(size_t)m * Kk + k0 + kq * 4];
        if (TWOA) {
          float4 vb = *(const float4*)&A2[(size_t)m * Kk + k0 + kq * 4];
          va.x += vb.x; va.y += vb.y; va.z += vb.z; va.w += vb.w;
        }
        int k = kq * 4;
        As[k][r] = va.x; As[k+1][r] = va.y; As[k+2][r] = va.z; As[k+3][r] = va.w;
      }
    }
    // ---- stage W tile (64 x 32) ----
    #pragma unroll
    for (int i = tid; i < 64 * 8; i += 256) {
      int kq = i & 7, nr = i >> 3;
      int n = bn * 64 + nr;
      float4 wv4 = make_float4(0.f, 0.f, 0.f, 0.f);
      if (n < Nn) wv4 = *(const float4*)&W[(size_t)n * Kk + k0 + kq * 4];
      int k = kq * 4;
      Ws[k][nr] = wv4.x; Ws[k+1][nr] = wv4.y; Ws[k+2][nr] = wv4.z; Ws[k+3][nr] = wv4.w;
    }
    __syncthreads();
    #pragma unroll
    for (int k = 0; k < 32; ++k) {
      float4 a0 = *(const float4*)&As[k][ty * 8];
      float4 a1 = *(const float4*)&As[k][ty * 8 + 4];
      float4 w0 = *(const float4*)&Ws[k][tx * 4];
      float av[8] = {a0.x, a0.y, a0.z, a0.w, a1.x, a1.y, a1.z, a1.w};
      float wv[4] = {w0.x, w0.y, w0.z, w0.w};
      #pragma unroll
      for (int i = 0; i < 8; ++i)
        #pragma unroll
        for (int j = 0; j < 4; ++j) acc[i][j] = fmaf(av[i], wv[j], acc[i][j]);
    }
    __syncthreads();
  }
  #pragma unroll
  for (int i = 0; i < 8; ++i) {
    int m = bm * 128 + ty * 8 + i;
    #pragma unroll
    for (int j = 0; j < 4; ++j) {
      int n = bn * 64 + tx * 4 + j;
      if (n >= Nn) continue;
      float v = acc[i][j] + (bias ? bias[n] : 0.f);
      if (ACT == 1) v = 0.5f * v * (1.f + erff(v * 0.70710678118f));
      if (OUTM == 0) Cmat[(size_t)m * ldc + n] = v;
      else {
        int b = m / LSEQ, l = m % LSEQ;
        Cmat[((size_t)(b * 96 + n)) * LSEQ + l] = v;
      }
    }
  }
}

// ---------------- causal depthwise conv1d (K=4) + silu, with direction ------
__global__ void conv1d_kernel(const float* __restrict__ xz, const float* __restrict__ cw,
                              const float* __restrict__ cb, float* __restrict__ xc) {
  int dir = blockIdx.y;
  int idx = blockIdx.x * 256 + threadIdx.x;   // 16000*192
  int e = idx % EC;
  int m = idx / EC;
  int b = m / LSEQ, s = m % LSEQ;
  const float* w = cw + dir * EC * 4 + e * 4;
  float acc = cb[dir * EC + e];
  #pragma unroll
  for (int k = 0; k < 4; ++k) {
    int sp = s - 3 + k;
    if (sp >= 0) {
      int p = dir ? (LSEQ - 1 - sp) : sp;
      acc += w[k] * xz[((size_t)(b * LSEQ + p)) * 384 + e];
    }
  }
  xc[(size_t)dir * BLEc + (size_t)m * EC + e] = siluf(acc);
}

// ---------------- dt = softplus(dbl[:,:6] @ dtw^T + dtb) ---------------------
__global__ void dt_kernel(const float* __restrict__ dbl, const float* __restrict__ dtw,
                          const float* __restrict__ dtb, float* __restrict__ dt) {
  int dir = blockIdx.y;
  int idx = blockIdx.x * 256 + threadIdx.x;   // 16000*192
  int e = idx % EC;
  int m = idx / EC;
  const float* db = dbl + (size_t)dir * BL38c + (size_t)m * 38;
  const float* wr = dtw + dir * EC * 6 + e * 6;
  float acc = dtb[dir * EC + e];
  #pragma unroll
  for (int r = 0; r < 6; ++r) acc += db[r] * wr[r];
  dt[(size_t)dir * BLEc + (size_t)m * EC + e] = softplusf(acc);
}

// ---------------- chunked selective scan, e-parallel -------------------------
// pass1: block=(c,b,dir), thread=e; local scan (h_in=0) keeping h[16],P[16] in regs.
__global__ void scan_pass1(const float* __restrict__ dt, const float* __restrict__ xc,
                           const float* __restrict__ dbl, const float* __restrict__ A_log,
                           float* __restrict__ Pm, float* __restrict__ hend) {
  int c = blockIdx.x, b = blockIdx.y, dir = blockIdx.z;
  int e = threadIdx.x;    // 192
  __shared__ float Bs[CHL][16];
  const float* dtp  = dt  + (size_t)dir * BLEc;
  const float* xcp  = xc  + (size_t)dir * BLEc;
  const float* dblp = dbl + (size_t)dir * BL38c;
  for (int i = e; i < CHL * 16; i += 192) {
    int s = i >> 4, n = i & 15;
    Bs[s][n] = dblp[(size_t)(b * LSEQ + c * CHL + s) * 38 + 6 + n];
  }
  __syncthreads();
  float Areg[16], h[16], P[16];
  #pragma unroll
  for (int n = 0; n < 16; ++n) {
    Areg[n] = -__expf(A_log[(dir * EC + e) * 16 + n]);
    h[n] = 0.f; P[n] = 1.f;
  }
  int base_s = b * LSEQ + c * CHL;
  for (int s = 0; s < CHL; ++s) {
    size_t row = (size_t)(base_s + s);
    float dtv = dtp[row * EC + e];
    float dx  = dtv * xcp[row * EC + e];
    #pragma unroll
    for (int n = 0; n < 16; ++n) {
      float a = __expf(dtv * Areg[n]);
      P[n] *= a;
      h[n] = fmaf(h[n], a, Bs[s][n] * dx);
    }
  }
  size_t base = (size_t)c * SUMW + ((size_t)(dir * 2 + b) * EC + e) * 16;
  #pragma unroll
  for (int n = 0; n < 16; ++n) { Pm[base + n] = P[n]; hend[base + n] = h[n]; }
}

// pass2: thread per (dir,b,e,n) lane within SUMW; serial over chunks (coalesced).
__global__ void scan_pass2(const float* __restrict__ Pm, const float* __restrict__ hend,
                           float* __restrict__ carry) {
  int idx = blockIdx.x * 256 + threadIdx.x;   // SUMW = 12288
  if (idx >= SUMW) return;
  float H = 0.f;
  for (int c = 0; c < NCH; ++c) {
    size_t p = (size_t)c * SUMW + idx;
    carry[p] = H;
    H = H * Pm[p] + hend[p];
  }
}

// pass3: recompute with carry-in; y = sum_n C*h + xc*D, gate silu(z), un-reverse.
__global__ void scan_pass3(const float* __restrict__ dt, const float* __restrict__ xc,
                           const float* __restrict__ dbl, const float* __restrict__ carry,
                           const float* __restrict__ A_log, const float* __restrict__ Dp,
                           const float* __restrict__ xz, float* __restrict__ ybuf) {
  int c = blockIdx.x, b = blockIdx.y, dir = blockIdx.z;
  int e = threadIdx.x;    // 192
  __shared__ float Bs[CHL][16];
  __shared__ float Cs[CHL][16];
  const float* dtp  = dt  + (size_t)dir * BLEc;
  const float* xcp  = xc  + (size_t)dir * BLEc;
  const float* dblp = dbl + (size_t)dir * BL38c;
  for (int i = e; i < CHL * 16; i += 192) {
    int s = i >> 4, n = i & 15;
    size_t r38 = (size_t)(b * LSEQ + c * CHL + s) * 38;
    Bs[s][n] = dblp[r38 + 6 + n];
    Cs[s][n] = dblp[r38 + 22 + n];
  }
  __syncthreads();
  float Areg[16], h[16];
  size_t cbase = (size_t)c * SUMW + ((size_t)(dir * 2 + b) * EC + e) * 16;
  #pragma unroll
  for (int n = 0; n < 16; ++n) {
    Areg[n] = -__expf(A_log[(dir * EC + e) * 16 + n]);
    h[n] = carry[cbase + n];
  }
  float Dv = Dp[dir * EC + e];
  int base_s = c * CHL;
  for (int s = 0; s < CHL; ++s) {
    int gs = base_s + s;
    size_t row = (size_t)(b * LSEQ + gs);
    float dtv = dtp[row * EC + e];
    float xcv = xcp[row * EC + e];
    float dx = dtv * xcv;
    float y = 0.f;
    #pragma unroll
    for (int n = 0; n < 16; ++n) {
      float a = __expf(dtv * Areg[n]);
      h[n] = fmaf(h[n], a, Bs[s][n] * dx);
      y = fmaf(h[n], Cs[s][n], y);
    }
    y = fmaf(xcv, Dv, y);
    int p = dir ? (LSEQ - 1 - gs) : gs;
    size_t prow = (size_t)(b * LSEQ + p);
    float zv = xz[prow * 384 + 192 + e];
    ybuf[(size_t)dir * BLEc + prow * EC + e] = y * siluf(zv);
  }
}

}  // namespace

extern "C" void kernel_launch(void* const* d_in, const int* in_sizes, int n_in,
                              void* d_out, int out_size, void* d_ws, size_t ws_size,
                              hipStream_t stream) {
  const float* x      = (const float*)d_in[0];
  const float* ds_w   = (const float*)d_in[1];
  const float* ds_b   = (const float*)d_in[2];
  const float* ds_ln_w= (const float*)d_in[3];
  const float* ds_ln_b= (const float*)d_in[4];
  const float* ln_w   = (const float*)d_in[5];
  const float* ln_b   = (const float*)d_in[6];
  const float* in_w   = (const float*)d_in[7];
  const float* conv_w = (const float*)d_in[8];
  const float* conv_b = (const float*)d_in[9];
  const float* xp_w   = (const float*)d_in[10];
  const float* dtp_w  = (const float*)d_in[11];
  const float* dtp_b  = (const float*)d_in[12];
  const float* A_log  = (const float*)d_in[13];
  const float* Dp     = (const float*)d_in[14];
  const float* out_w  = (const float*)d_in[15];
  const float* f_ln_w = (const float*)d_in[16];
  const float* f_ln_b = (const float*)d_in[17];
  const float* fc1_w  = (const float*)d_in[18];
  const float* fc1_b  = (const float*)d_in[19];
  const float* fc2_w  = (const float*)d_in[20];
  const float* fc2_b  = (const float*)d_in[21];
  float* outp = (float*)d_out;
  float* ws = (float*)d_ws;

  size_t o = 0;
  float* xf    = ws + o;  o += 1536000;
  float* xn    = ws + o;  o += 1536000;
  float* xz    = ws + o;  o += 6144000;
  float* xcb   = ws + o;  o += 2 * (size_t)BLEc;
  float* dblb  = ws + o;  o += 2 * (size_t)BL38c;
  float* dtbuf = ws + o;  o += 2 * (size_t)BLEc;
  float* ybuf  = ws + o;  o += 2 * (size_t)BLEc;
  float* carry = ws + o;  o += (size_t)NCH * SUMW;
  // Pm/hend are dead once pass2 has run; alias them onto ybuf (written in pass3).
  float* Pm    = ybuf;
  float* hendb = ybuf + (size_t)NCH * SUMW;

  // Stage A: ds-conv as fused im2col-GEMM (M=16000, N=96, K=384), then row-LN.
  gemm_k<0, 0, false, true><<<dim3(125, 2), 256, 0, stream>>>(
      x, nullptr, ds_w, ds_b, xn, MROWS, 96, 384, 96);
  ln_row_kernel<<<4000, 256, 0, stream>>>(xn, ds_ln_w, ds_ln_b, xf, 1e-6f);

  for (int i = 0; i < 2; ++i) {
    ln_row_kernel<<<4000, 256, 0, stream>>>(xf, ln_w + i * 96, ln_b + i * 96, xn, 1e-5f);
    gemm_k<0, 0, false, false><<<dim3(125, 6), 256, 0, stream>>>(
        xn, nullptr, in_w + (size_t)i * 384 * 96, nullptr, xz, MROWS, 384, 96, 384);
    conv1d_kernel<<<dim3(12000, 2), 256, 0, stream>>>(
        xz, conv_w + (size_t)i * 2 * EC * 4, conv_b + (size_t)i * 2 * EC, xcb);
    for (int dir = 0; dir < 2; ++dir) {
      gemm_k<0, 0, false, false><<<dim3(125, 1), 256, 0, stream>>>(
          xcb + (size_t)dir * BLEc, nullptr,
          xp_w + ((size_t)i * 2 + dir) * 38 * EC, nullptr,
          dblb + (size_t)dir * BL38c, MROWS, 38, EC, 38);
    }
    dt_kernel<<<dim3(12000, 2), 256, 0, stream>>>(
        dblb, dtp_w + (size_t)i * 2 * EC * 6, dtp_b + (size_t)i * 2 * EC, dtbuf);
    scan_pass1<<<dim3(NCH, 2, 2), 192, 0, stream>>>(
        dtbuf, xcb, dblb, A_log + (size_t)i * 2 * EC * NC_, Pm, hendb);
    scan_pass2<<<48, 256, 0, stream>>>(Pm, hendb, carry);
    scan_pass3<<<dim3(NCH, 2, 2), 192, 0, stream>>>(
        dtbuf, xcb, dblb, carry, A_log + (size_t)i * 2 * EC * NC_,
        Dp + (size_t)i * 2 * EC, xz, ybuf);
    gemm_k<0, 0, true, false><<<dim3(125, 2), 256, 0, stream>>>(
        ybuf, ybuf + BLEc, out_w + (size_t)i * 96 * EC, nullptr, xf, MROWS, 96, EC, 96);
  }

  ln_row_kernel<<<4000, 256, 0, stream>>>(xf, f_ln_w, f_ln_b, xn, 1e-6f);
  gemm_k<1, 0, false, false><<<dim3(125, 6), 256, 0, stream>>>(
      xn, nullptr, fc1_w, fc1_b, xz, MROWS, 384, 96, 384);
  gemm_k<0, 1, false, false><<<dim3(125, 2), 256, 0, stream>>>(
      xz, nullptr, fc2_w, fc2_b, outp, MROWS, 96, 384, 96);
}

// Round 3
// 654.115 us; speedup vs baseline: 2.1357x; 1.0628x over previous
//
#include <hip/hip_runtime.h>
#include <math.h>

namespace {

constexpr int BATCH = 2;
constexpr int LSEQ  = 8000;
constexpr int MROWS = BATCH * LSEQ;   // 16000
constexpr int EC    = 192;
constexpr int NC_   = 16;
constexpr int NCH   = 160;            // chunks per sequence
constexpr int CHL   = 50;             // chunk length (160*50 = 8000)
constexpr int BLEc  = MROWS * EC;     // 3,072,000
constexpr int BL38c = MROWS * 38;     // 608,000
constexpr int SUMW  = 2 * 2 * EC * NC_;  // 12288 chunk-summary width

__device__ __forceinline__ float siluf(float x) { return x / (1.f + __expf(-x)); }
__device__ __forceinline__ float softplusf(float x) {
  if (x > 20.f) return x;
  return log1pf(__expf(x));
}

// ---------------- row LN over last dim 96 (wave per row) ---------------------
__global__ void ln_row_kernel(const float* __restrict__ in, const float* __restrict__ w,
                              const float* __restrict__ bv, float* __restrict__ out, float eps) {
  int lane = threadIdx.x & 63;
  int row = blockIdx.x * 4 + (threadIdx.x >> 6);   // 4000 blocks * 4 = 16000
  const float* r = in + (size_t)row * 96;
  float v0 = r[lane];
  float v1 = (lane < 32) ? r[64 + lane] : 0.f;
  float s = v0 + v1, s2 = v0*v0 + v1*v1;
  #pragma unroll
  for (int o = 32; o; o >>= 1) { s += __shfl_xor(s, o); s2 += __shfl_xor(s2, o); }
  float m = s * (1.f/96.f);
  float var = s2 * (1.f/96.f) - m * m;
  float rs = rsqrtf(var + eps);
  float* orow = out + (size_t)row * 96;
  orow[lane] = (v0 - m) * rs * w[lane] + bv[lane];
  if (lane < 32) orow[64 + lane] = (v1 - m) * rs * w[64 + lane] + bv[64 + lane];
}

// ---------------- tiled fp32 GEMM: C[m,n] = act(sum_k A[m,k]W[n,k]+bias) -----
// Tile 32x64, BK=32, 128 threads, 4x4 acc/thread, K-transposed LDS.
// LDS strides: As 34 (writes 2-way), Ws 66 (writes 2-way); float2 frags (8B aligned).
// blockIdx.z batches independent problems (dir): A/W/C advance by given strides.
// ACT: 0 none, 1 exact gelu.  OUTM: 0 row-major (ldc), 1 scatter (b,n,l).
// IM2COL: A-tile gathered from x (2,48,40,40,40) for the stride-2 k-2 ds-conv.
// M multiple of 32; Kk multiple of 32.
template<int ACT, int OUTM, bool TWOA, bool IM2COL>
__global__ __launch_bounds__(128) void gemm_k(const float* __restrict__ A, const float* __restrict__ A2,
                      const float* __restrict__ W, const float* __restrict__ bias,
                      float* __restrict__ Cmat, int M, int Nn, int Kk, int ldc,
                      size_t aStride, size_t wStride, size_t cStride) {
  __shared__ float As[32][34];   // [k][r]
  __shared__ float Ws[32][66];   // [k][n]
  A += aStride * blockIdx.z;
  if (TWOA) A2 += aStride * blockIdx.z;
  W += wStride * blockIdx.z;
  Cmat += cStride * blockIdx.z;
  int tid = threadIdx.x;
  int bm = blockIdx.x, bn = blockIdx.y;
  int ty = tid >> 4, tx = tid & 15;   // ty: 8 groups of 4 rows, tx: 16 groups of 4 cols
  float acc[4][4] = {};
  for (int k0 = 0; k0 < Kk; k0 += 32) {
    // ---- stage A tile (32 rows x 32 k) ----
    if (IM2COL) {
      // col = c*8 + kd*4 + kh*2 + kw ; read float2 (kw pair) per slot
      #pragma unroll
      for (int i = tid; i < 32 * 16; i += 128) {
        int p  = i & 3;            // (kd,kh) pair
        int c4 = (i >> 2) & 3;     // channel within tile
        int r  = i >> 4;           // row 0..31
        int m = bm * 32 + r;
        int b = m / 8000, l = m % 8000;
        int dd = l / 400, hh = (l / 20) % 20, wd = l % 20;
        int off = (p >> 1) * 1600 + (p & 1) * 40;
        const float* xp = A + ((size_t)b * 48 + (k0 >> 3) + c4) * 64000
                            + dd * 3200 + hh * 80 + wd * 2 + off;
        float2 v = *(const float2*)xp;
        int k = c4 * 8 + p * 2;
        As[k][r] = v.x;
        As[k + 1][r] = v.y;
      }
    } else {
      #pragma unroll
      for (int i = tid; i < 32 * 8; i += 128) {
        int kq = i & 7, r = i >> 3;
        int m = bm * 32 + r;
        float4 va = *(const float4*)&A[(size_t)m * Kk + k0 + kq * 4];
        if (TWOA) {
          float4 vb = *(const float4*)&A2[(size_t)m * Kk + k0 + kq * 4];
          va.x += vb.x; va.y += vb.y; va.z += vb.z; va.w += vb.w;
        }
        int k = kq * 4;
        As[k][r] = va.x; As[k+1][r] = va.y; As[k+2][r] = va.z; As[k+3][r] = va.w;
      }
    }
    // ---- stage W tile (64 n x 32 k) ----
    #pragma unroll
    for (int i = tid; i < 64 * 8; i += 128) {
      int kq = i & 7, nr = i >> 3;
      int n = bn * 64 + nr;
      float4 wv4 = make_float4(0.f, 0.f, 0.f, 0.f);
      if (n < Nn) wv4 = *(const float4*)&W[(size_t)n * Kk + k0 + kq * 4];
      int k = kq * 4;
      Ws[k][nr] = wv4.x; Ws[k+1][nr] = wv4.y; Ws[k+2][nr] = wv4.z; Ws[k+3][nr] = wv4.w;
    }
    __syncthreads();
    #pragma unroll
    for (int k = 0; k < 32; ++k) {
      float2 a0 = *(const float2*)&As[k][ty * 4];
      float2 a1 = *(const float2*)&As[k][ty * 4 + 2];
      float2 w0 = *(const float2*)&Ws[k][tx * 4];
      float2 w1 = *(const float2*)&Ws[k][tx * 4 + 2];
      float av[4] = {a0.x, a0.y, a1.x, a1.y};
      float wv[4] = {w0.x, w0.y, w1.x, w1.y};
      #pragma unroll
      for (int i = 0; i < 4; ++i)
        #pragma unroll
        for (int j = 0; j < 4; ++j) acc[i][j] = fmaf(av[i], wv[j], acc[i][j]);
    }
    __syncthreads();
  }
  int n0 = bn * 64 + tx * 4;
  if (OUTM == 1) {
    // scatter: column-major (b, n, l); 4 consecutive m -> contiguous float4 in l
    int m0 = bm * 32 + ty * 4;
    int b = m0 / LSEQ, l0 = m0 % LSEQ;
    #pragma unroll
    for (int j = 0; j < 4; ++j) {
      int n = n0 + j;
      if (n >= Nn) continue;
      float bj = bias ? bias[n] : 0.f;
      float4 v = make_float4(acc[0][j] + bj, acc[1][j] + bj, acc[2][j] + bj, acc[3][j] + bj);
      *(float4*)&Cmat[((size_t)(b * 96 + n)) * LSEQ + l0] = v;
    }
  } else if (((ldc & 3) == 0) && (n0 + 4 <= Nn)) {
    #pragma unroll
    for (int i = 0; i < 4; ++i) {
      int m = bm * 32 + ty * 4 + i;
      float4 v;
      float* vp = &v.x;
      #pragma unroll
      for (int j = 0; j < 4; ++j) {
        float t = acc[i][j] + (bias ? bias[n0 + j] : 0.f);
        if (ACT == 1) t = 0.5f * t * (1.f + erff(t * 0.70710678118f));
        vp[j] = t;
      }
      *(float4*)&Cmat[(size_t)m * ldc + n0] = v;
    }
  } else {
    #pragma unroll
    for (int i = 0; i < 4; ++i) {
      int m = bm * 32 + ty * 4 + i;
      #pragma unroll
      for (int j = 0; j < 4; ++j) {
        int n = n0 + j;
        if (n >= Nn) continue;
        float t = acc[i][j] + (bias ? bias[n] : 0.f);
        if (ACT == 1) t = 0.5f * t * (1.f + erff(t * 0.70710678118f));
        Cmat[(size_t)m * ldc + n] = t;
      }
    }
  }
}

// ---------------- causal depthwise conv1d (K=4) + silu, float2 over e -------
__global__ void conv1d_kernel(const float* __restrict__ xz, const float* __restrict__ cw,
                              const float* __restrict__ cb, float* __restrict__ xc) {
  int dir = blockIdx.y;
  int idx = blockIdx.x * 256 + threadIdx.x;   // 16000*96
  int e2 = idx % 96;
  int m = idx / 96;
  int b = m / LSEQ, s = m % LSEQ;
  int e = e2 * 2;
  const float* w = cw + dir * EC * 4 + e * 4;
  float2 acc = make_float2(cb[dir * EC + e], cb[dir * EC + e + 1]);
  #pragma unroll
  for (int k = 0; k < 4; ++k) {
    int sp = s - 3 + k;
    if (sp >= 0) {
      int p = dir ? (LSEQ - 1 - sp) : sp;
      float2 v = *(const float2*)&xz[((size_t)(b * LSEQ + p)) * 384 + e];
      acc.x = fmaf(w[k], v.x, acc.x);
      acc.y = fmaf(w[4 + k], v.y, acc.y);
    }
  }
  float2 r = make_float2(siluf(acc.x), siluf(acc.y));
  *(float2*)&xc[(size_t)dir * BLEc + (size_t)m * EC + e] = r;
}

// ---------------- dt = softplus(dbl[:,:6] @ dtw^T + dtb) ---------------------
__global__ void dt_kernel(const float* __restrict__ dbl, const float* __restrict__ dtw,
                          const float* __restrict__ dtb, float* __restrict__ dt) {
  int dir = blockIdx.y;
  int idx = blockIdx.x * 256 + threadIdx.x;   // 16000*192
  int e = idx % EC;
  int m = idx / EC;
  const float* db = dbl + (size_t)dir * BL38c + (size_t)m * 38;
  const float* wr = dtw + dir * EC * 6 + e * 6;
  float acc = dtb[dir * EC + e];
  #pragma unroll
  for (int r = 0; r < 6; ++r) acc += db[r] * wr[r];
  dt[(size_t)dir * BLEc + (size_t)m * EC + e] = softplusf(acc);
}

// ---------------- chunked selective scan, e-parallel -------------------------
__global__ void scan_pass1(const float* __restrict__ dt, const float* __restrict__ xc,
                           const float* __restrict__ dbl, const float* __restrict__ A_log,
                           float* __restrict__ Pm, float* __restrict__ hend) {
  int c = blockIdx.x, b = blockIdx.y, dir = blockIdx.z;
  int e = threadIdx.x;    // 192
  __shared__ float Bs[CHL][16];
  const float* dtp  = dt  + (size_t)dir * BLEc;
  const float* xcp  = xc  + (size_t)dir * BLEc;
  const float* dblp = dbl + (size_t)dir * BL38c;
  for (int i = e; i < CHL * 16; i += 192) {
    int s = i >> 4, n = i & 15;
    Bs[s][n] = dblp[(size_t)(b * LSEQ + c * CHL + s) * 38 + 6 + n];
  }
  __syncthreads();
  float Areg[16], h[16], P[16];
  #pragma unroll
  for (int n = 0; n < 16; ++n) {
    Areg[n] = -__expf(A_log[(dir * EC + e) * 16 + n]);
    h[n] = 0.f; P[n] = 1.f;
  }
  int base_s = b * LSEQ + c * CHL;
  for (int s = 0; s < CHL; ++s) {
    size_t row = (size_t)(base_s + s);
    float dtv = dtp[row * EC + e];
    float dx  = dtv * xcp[row * EC + e];
    #pragma unroll
    for (int n = 0; n < 16; ++n) {
      float a = __expf(dtv * Areg[n]);
      P[n] *= a;
      h[n] = fmaf(h[n], a, Bs[s][n] * dx);
    }
  }
  size_t base = (size_t)c * SUMW + ((size_t)(dir * 2 + b) * EC + e) * 16;
  #pragma unroll
  for (int n = 0; n < 16; ++n) { Pm[base + n] = P[n]; hend[base + n] = h[n]; }
}

__global__ void scan_pass2(const float* __restrict__ Pm, const float* __restrict__ hend,
                           float* __restrict__ carry) {
  int idx = blockIdx.x * 256 + threadIdx.x;   // SUMW = 12288
  if (idx >= SUMW) return;
  float H = 0.f;
  for (int c = 0; c < NCH; ++c) {
    size_t p = (size_t)c * SUMW + idx;
    carry[p] = H;
    H = H * Pm[p] + hend[p];
  }
}

__global__ void scan_pass3(const float* __restrict__ dt, const float* __restrict__ xc,
                           const float* __restrict__ dbl, const float* __restrict__ carry,
                           const float* __restrict__ A_log, const float* __restrict__ Dp,
                           const float* __restrict__ xz, float* __restrict__ ybuf) {
  int c = blockIdx.x, b = blockIdx.y, dir = blockIdx.z;
  int e = threadIdx.x;    // 192
  __shared__ float Bs[CHL][16];
  __shared__ float Cs[CHL][16];
  const float* dtp  = dt  + (size_t)dir * BLEc;
  const float* xcp  = xc  + (size_t)dir * BLEc;
  const float* dblp = dbl + (size_t)dir * BL38c;
  for (int i = e; i < CHL * 16; i += 192) {
    int s = i >> 4, n = i & 15;
    size_t r38 = (size_t)(b * LSEQ + c * CHL + s) * 38;
    Bs[s][n] = dblp[r38 + 6 + n];
    Cs[s][n] = dblp[r38 + 22 + n];
  }
  __syncthreads();
  float Areg[16], h[16];
  size_t cbase = (size_t)c * SUMW + ((size_t)(dir * 2 + b) * EC + e) * 16;
  #pragma unroll
  for (int n = 0; n < 16; ++n) {
    Areg[n] = -__expf(A_log[(dir * EC + e) * 16 + n]);
    h[n] = carry[cbase + n];
  }
  float Dv = Dp[dir * EC + e];
  int base_s = c * CHL;
  for (int s = 0; s < CHL; ++s) {
    int gs = base_s + s;
    size_t row = (size_t)(b * LSEQ + gs);
    float dtv = dtp[row * EC + e];
    float xcv = xcp[row * EC + e];
    float dx = dtv * xcv;
    float y = 0.f;
    #pragma unroll
    for (int n = 0; n < 16; ++n) {
      float a = __expf(dtv * Areg[n]);
      h[n] = fmaf(h[n], a, Bs[s][n] * dx);
      y = fmaf(h[n], Cs[s][n], y);
    }
    y = fmaf(xcv, Dv, y);
    int p = dir ? (LSEQ - 1 - gs) : gs;
    size_t prow = (size_t)(b * LSEQ + p);
    float zv = xz[prow * 384 + 192 + e];
    ybuf[(size_t)dir * BLEc + prow * EC + e] = y * siluf(zv);
  }
}

}  // namespace

extern "C" void kernel_launch(void* const* d_in, const int* in_sizes, int n_in,
                              void* d_out, int out_size, void* d_ws, size_t ws_size,
                              hipStream_t stream) {
  const float* x      = (const float*)d_in[0];
  const float* ds_w   = (const float*)d_in[1];
  const float* ds_b   = (const float*)d_in[2];
  const float* ds_ln_w= (const float*)d_in[3];
  const float* ds_ln_b= (const float*)d_in[4];
  const float* ln_w   = (const float*)d_in[5];
  const float* ln_b   = (const float*)d_in[6];
  const float* in_w   = (const float*)d_in[7];
  const float* conv_w = (const float*)d_in[8];
  const float* conv_b = (const float*)d_in[9];
  const float* xp_w   = (const float*)d_in[10];
  const float* dtp_w  = (const float*)d_in[11];
  const float* dtp_b  = (const float*)d_in[12];
  const float* A_log  = (const float*)d_in[13];
  const float* Dp     = (const float*)d_in[14];
  const float* out_w  = (const float*)d_in[15];
  const float* f_ln_w = (const float*)d_in[16];
  const float* f_ln_b = (const float*)d_in[17];
  const float* fc1_w  = (const float*)d_in[18];
  const float* fc1_b  = (const float*)d_in[19];
  const float* fc2_w  = (const float*)d_in[20];
  const float* fc2_b  = (const float*)d_in[21];
  float* outp = (float*)d_out;
  float* ws = (float*)d_ws;

  size_t o = 0;
  float* xf    = ws + o;  o += 1536000;
  float* xn    = ws + o;  o += 1536000;
  float* xz    = ws + o;  o += 6144000;
  float* xcb   = ws + o;  o += 2 * (size_t)BLEc;
  float* dblb  = ws + o;  o += 2 * (size_t)BL38c;
  float* dtbuf = ws + o;  o += 2 * (size_t)BLEc;
  float* ybuf  = ws + o;  o += 2 * (size_t)BLEc;
  float* carry = ws + o;  o += (size_t)NCH * SUMW;
  // Pm/hend dead after pass2; alias onto ybuf (written only in pass3).
  float* Pm    = ybuf;
  float* hendb = ybuf + (size_t)NCH * SUMW;

  // Stage A: ds-conv as fused im2col-GEMM (M=16000, N=96, K=384), then row-LN.
  gemm_k<0, 0, false, true><<<dim3(500, 2, 1), 128, 0, stream>>>(
      x, nullptr, ds_w, ds_b, xn, MROWS, 96, 384, 96, 0, 0, 0);
  ln_row_kernel<<<4000, 256, 0, stream>>>(xn, ds_ln_w, ds_ln_b, xf, 1e-6f);

  for (int i = 0; i < 2; ++i) {
    ln_row_kernel<<<4000, 256, 0, stream>>>(xf, ln_w + i * 96, ln_b + i * 96, xn, 1e-5f);
    gemm_k<0, 0, false, false><<<dim3(500, 6, 1), 128, 0, stream>>>(
        xn, nullptr, in_w + (size_t)i * 384 * 96, nullptr, xz, MROWS, 384, 96, 384, 0, 0, 0);
    conv1d_kernel<<<dim3(6000, 2), 256, 0, stream>>>(
        xz, conv_w + (size_t)i * 2 * EC * 4, conv_b + (size_t)i * 2 * EC, xcb);
    gemm_k<0, 0, false, false><<<dim3(500, 1, 2), 128, 0, stream>>>(
        xcb, nullptr, xp_w + (size_t)i * 2 * 38 * EC, nullptr, dblb,
        MROWS, 38, EC, 38, (size_t)BLEc, (size_t)38 * EC, (size_t)BL38c);
    dt_kernel<<<dim3(12000, 2), 256, 0, stream>>>(
        dblb, dtp_w + (size_t)i * 2 * EC * 6, dtp_b + (size_t)i * 2 * EC, dtbuf);
    scan_pass1<<<dim3(NCH, 2, 2), 192, 0, stream>>>(
        dtbuf, xcb, dblb, A_log + (size_t)i * 2 * EC * NC_, Pm, hendb);
    scan_pass2<<<48, 256, 0, stream>>>(Pm, hendb, carry);
    scan_pass3<<<dim3(NCH, 2, 2), 192, 0, stream>>>(
        dtbuf, xcb, dblb, carry, A_log + (size_t)i * 2 * EC * NC_,
        Dp + (size_t)i * 2 * EC, xz, ybuf);
    gemm_k<0, 0, true, false><<<dim3(500, 2, 1), 128, 0, stream>>>(
        ybuf, ybuf + BLEc, out_w + (size_t)i * 96 * EC, nullptr, xf,
        MROWS, 96, EC, 96, 0, 0, 0);
  }

  ln_row_kernel<<<4000, 256, 0, stream>>>(xf, f_ln_w, f_ln_b, xn, 1e-6f);
  gemm_k<1, 0, false, false><<<dim3(500, 6, 1), 128, 0, stream>>>(
      xn, nullptr, fc1_w, fc1_b, xz, MROWS, 384, 96, 384, 0, 0, 0);
  gemm_k<0, 1, false, false><<<dim3(500, 2, 1), 128, 0, stream>>>(
      xz, nullptr, fc2_w, fc2_b, outp, MROWS, 96, 384, 96, 0, 0, 0);
}

// Round 5
// 625.147 us; speedup vs baseline: 2.2347x; 1.0463x over previous
//
#include <hip/hip_runtime.h>
#include <hip/hip_bf16.h>
#include <math.h>

namespace {

constexpr int LSEQ  = 8000;
constexpr int MROWS = 16000;          // 2 * 8000
constexpr int EC    = 192;
constexpr int NCH   = 160;            // chunks per sequence
constexpr int CHL   = 50;             // chunk length
constexpr int BLEc  = MROWS * EC;     // 3,072,000
constexpr int BL38c = MROWS * 38;     // 608,000
constexpr int SUMW  = 2 * 2 * EC * 16;  // 12288

typedef __attribute__((ext_vector_type(8))) short bf16x8;
typedef __attribute__((ext_vector_type(4))) float f32x4;

__device__ __forceinline__ float siluf(float x) { return x / (1.f + __expf(-x)); }
__device__ __forceinline__ float softplusf(float x) {
  if (x > 20.f) return x;
  return log1pf(__expf(x));
}
__device__ __forceinline__ short f2bf(float f) {
  __hip_bfloat16 h = __float2bfloat16(f);
  return *reinterpret_cast<short*>(&h);
}
__device__ __forceinline__ float bf2f(short s) {
  __hip_bfloat16 h;
  *reinterpret_cast<short*>(&h) = s;
  return __bfloat162float(h);
}
// split fp32 -> (hi, lo) bf16 pair: x ~= hi + lo with ~2^-17 representation err
__device__ __forceinline__ void splitbf(float x, short& hi, short& lo) {
  hi = f2bf(x);
  lo = f2bf(x - bf2f(hi));
}

// ---------------- row LN over last dim 96 (wave per row), f32 out ------------
__global__ void ln_row_kernel(const float* __restrict__ in, const float* __restrict__ w,
                              const float* __restrict__ bv, float* __restrict__ out, float eps) {
  int lane = threadIdx.x & 63;
  int row = blockIdx.x * 4 + (threadIdx.x >> 6);   // 4000 blocks * 4 = 16000
  const float* r = in + (size_t)row * 96;
  float v0 = r[lane];
  float v1 = (lane < 32) ? r[64 + lane] : 0.f;
  float s = v0 + v1, s2 = v0 * v0 + v1 * v1;
  #pragma unroll
  for (int o = 32; o; o >>= 1) { s += __shfl_xor(s, o); s2 += __shfl_xor(s2, o); }
  float m = s * (1.f / 96.f);
  float var = s2 * (1.f / 96.f) - m * m;
  float rs = rsqrtf(var + eps);
  float* orow = out + (size_t)row * 96;
  orow[lane] = (v0 - m) * rs * w[lane] + bv[lane];
  if (lane < 32) orow[64 + lane] = (v1 - m) * rs * w[64 + lane] + bv[64 + lane];
}

// ---------------- split-bf16 MFMA GEMM: C[m,n] = act(sum_k A[m,k]W[n,k]+bias) --
// A, W fp32 in memory; staged as (hi,lo) bf16 pairs; 3 MFMAs per fragment pair:
//   hi*hi + hi*lo + lo*hi  ->  ~2^-16 relative error, fp32 accumulate.
// Tile 64x64, BK=128, 256 threads (4 waves = 2x2 quadrants of 32x32).
// AMODE: 0 A fp32 [M][Kk]; 1 (A+A2) fp32 summed; 2 im2col from x (2,48,40,40,40).
// ACT: 0 none, 1 exact gelu.  OUTM: 0 row-major f32 (ldc); 1 transpose (b,n,l) f32.
template<int ACT, int OUTM, int AMODE>
__global__ __launch_bounds__(256) void gemm_mfma(
    const float* __restrict__ A, const float* __restrict__ A2,
    const float* __restrict__ W, const float* __restrict__ bias,
    float* __restrict__ Cp, int M, int Nn, int Kk, int ldc,
    size_t aStride, size_t wStride, size_t cStride) {
  __shared__ short Al[2][64][136];   // [hi/lo][row][k], row stride 272B
  __shared__ short Bl[2][64][136];
  int tid = threadIdx.x;
  int lane = tid & 63, wid = tid >> 6;
  int wr = wid >> 1, wc = wid & 1;
  int bm = blockIdx.x, bn = blockIdx.y;
  int m0 = bm * 64;
  A += aStride * blockIdx.z;
  if (AMODE == 1) A2 += aStride * blockIdx.z;
  W += wStride * blockIdx.z;
  Cp += cStride * blockIdx.z;
  f32x4 acc[2][2] = {};
  for (int k0 = 0; k0 < Kk; k0 += 128) {
    int Kcur = Kk - k0; if (Kcur > 128) Kcur = 128;
    // ---- stage A ----
    if (AMODE == 2) {
      #pragma unroll
      for (int i = tid; i < 64 * 64; i += 256) {
        int p = i & 3, c16 = (i >> 2) & 15, r = i >> 6;
        int m = m0 + r;
        int b = m / 8000, l = m % 8000;
        int dd = l / 400, hh = (l / 20) % 20, wd = l % 20;
        int off = (p >> 1) * 1600 + (p & 1) * 40;
        const float* xp = A + ((size_t)b * 48 + (k0 >> 3) + c16) * 64000
                            + dd * 3200 + hh * 80 + wd * 2 + off;
        float2 v = *(const float2*)xp;
        int k = c16 * 8 + p * 2;
        splitbf(v.x, Al[0][r][k], Al[1][r][k]);
        splitbf(v.y, Al[0][r][k + 1], Al[1][r][k + 1]);
      }
    } else {
      #pragma unroll
      for (int i = tid; i < 64 * 16; i += 256) {
        int kq = i & 15, r = i >> 4;
        if (kq * 8 < Kcur) {
          const float* ap = A + (size_t)(m0 + r) * Kk + k0 + kq * 8;
          float4 v0 = *(const float4*)ap;
          float4 v1 = *(const float4*)(ap + 4);
          if (AMODE == 1) {
            const float* bp = A2 + (size_t)(m0 + r) * Kk + k0 + kq * 8;
            float4 u0 = *(const float4*)bp;
            float4 u1 = *(const float4*)(bp + 4);
            v0.x += u0.x; v0.y += u0.y; v0.z += u0.z; v0.w += u0.w;
            v1.x += u1.x; v1.y += u1.y; v1.z += u1.z; v1.w += u1.w;
          }
          float vals[8] = {v0.x, v0.y, v0.z, v0.w, v1.x, v1.y, v1.z, v1.w};
          bf16x8 hi, lo;
          #pragma unroll
          for (int j = 0; j < 8; ++j) { short h, l2; splitbf(vals[j], h, l2); hi[j] = h; lo[j] = l2; }
          *(bf16x8*)&Al[0][r][kq * 8] = hi;
          *(bf16x8*)&Al[1][r][kq * 8] = lo;
        }
      }
    }
    // ---- stage W ----
    #pragma unroll
    for (int i = tid; i < 64 * 16; i += 256) {
      int kq = i & 15, nr = i >> 4;
      if (kq * 8 < Kcur) {
        int n = bn * 64 + nr;
        bf16x8 hi = {0,0,0,0,0,0,0,0}, lo = {0,0,0,0,0,0,0,0};
        if (n < Nn) {
          const float* wp = &W[(size_t)n * Kk + k0 + kq * 8];
          float4 w0 = *(const float4*)wp;
          float4 w1 = *(const float4*)(wp + 4);
          float vals[8] = {w0.x, w0.y, w0.z, w0.w, w1.x, w1.y, w1.z, w1.w};
          #pragma unroll
          for (int j = 0; j < 8; ++j) { short h, l2; splitbf(vals[j], h, l2); hi[j] = h; lo[j] = l2; }
        }
        *(bf16x8*)&Bl[0][nr][kq * 8] = hi;
        *(bf16x8*)&Bl[1][nr][kq * 8] = lo;
      }
    }
    __syncthreads();
    int mr = lane & 15;
    int kq0 = (lane >> 4) * 8;
    #pragma unroll
    for (int ks = 0; ks < 4; ++ks) {
      if (ks * 32 >= Kcur) break;
      int kb = ks * 32 + kq0;
      bf16x8 a0h = *(const bf16x8*)&Al[0][wr * 32 + mr][kb];
      bf16x8 a0l = *(const bf16x8*)&Al[1][wr * 32 + mr][kb];
      bf16x8 a1h = *(const bf16x8*)&Al[0][wr * 32 + 16 + mr][kb];
      bf16x8 a1l = *(const bf16x8*)&Al[1][wr * 32 + 16 + mr][kb];
      bf16x8 b0h = *(const bf16x8*)&Bl[0][wc * 32 + mr][kb];
      bf16x8 b0l = *(const bf16x8*)&Bl[1][wc * 32 + mr][kb];
      bf16x8 b1h = *(const bf16x8*)&Bl[0][wc * 32 + 16 + mr][kb];
      bf16x8 b1l = *(const bf16x8*)&Bl[1][wc * 32 + 16 + mr][kb];
      acc[0][0] = __builtin_amdgcn_mfma_f32_16x16x32_bf16(a0h, b0h, acc[0][0], 0, 0, 0);
      acc[0][0] = __builtin_amdgcn_mfma_f32_16x16x32_bf16(a0h, b0l, acc[0][0], 0, 0, 0);
      acc[0][0] = __builtin_amdgcn_mfma_f32_16x16x32_bf16(a0l, b0h, acc[0][0], 0, 0, 0);
      acc[0][1] = __builtin_amdgcn_mfma_f32_16x16x32_bf16(a0h, b1h, acc[0][1], 0, 0, 0);
      acc[0][1] = __builtin_amdgcn_mfma_f32_16x16x32_bf16(a0h, b1l, acc[0][1], 0, 0, 0);
      acc[0][1] = __builtin_amdgcn_mfma_f32_16x16x32_bf16(a0l, b1h, acc[0][1], 0, 0, 0);
      acc[1][0] = __builtin_amdgcn_mfma_f32_16x16x32_bf16(a1h, b0h, acc[1][0], 0, 0, 0);
      acc[1][0] = __builtin_amdgcn_mfma_f32_16x16x32_bf16(a1h, b0l, acc[1][0], 0, 0, 0);
      acc[1][0] = __builtin_amdgcn_mfma_f32_16x16x32_bf16(a1l, b0h, acc[1][0], 0, 0, 0);
      acc[1][1] = __builtin_amdgcn_mfma_f32_16x16x32_bf16(a1h, b1h, acc[1][1], 0, 0, 0);
      acc[1][1] = __builtin_amdgcn_mfma_f32_16x16x32_bf16(a1h, b1l, acc[1][1], 0, 0, 0);
      acc[1][1] = __builtin_amdgcn_mfma_f32_16x16x32_bf16(a1l, b1h, acc[1][1], 0, 0, 0);
    }
    __syncthreads();
  }
  // ---- epilogue ----
  if (OUTM == 0) {
    #pragma unroll
    for (int fm = 0; fm < 2; ++fm) {
      #pragma unroll
      for (int fn = 0; fn < 2; ++fn) {
        int nn = bn * 64 + wc * 32 + fn * 16 + (lane & 15);
        if (nn >= Nn) continue;
        float bj = bias ? bias[nn] : 0.f;
        #pragma unroll
        for (int r = 0; r < 4; ++r) {
          int mm = m0 + wr * 32 + fm * 16 + (lane >> 4) * 4 + r;
          float v = acc[fm][fn][r] + bj;
          if (ACT == 1) v = 0.5f * v * (1.f + erff(v * 0.70710678118f));
          Cp[(size_t)mm * ldc + nn] = v;
        }
      }
    }
  } else {
    // transpose 64x64 tile via LDS (overlay on Al: 64*65*4 = 16640 <= 34816 B)
    float* Tr = (float*)&Al[0][0][0];
    #pragma unroll
    for (int fm = 0; fm < 2; ++fm)
      #pragma unroll
      for (int fn = 0; fn < 2; ++fn)
        #pragma unroll
        for (int r = 0; r < 4; ++r) {
          int ml = wr * 32 + fm * 16 + (lane >> 4) * 4 + r;
          int nl = wc * 32 + fn * 16 + (lane & 15);
          Tr[ml * 65 + nl] = acc[fm][fn][r];
        }
    __syncthreads();
    int n = tid & 63, q = tid >> 6;
    int nn = bn * 64 + n;
    if (nn < Nn) {
      float bj = bias ? bias[nn] : 0.f;
      int b = m0 / LSEQ;
      int l0 = m0 % LSEQ + q * 16;
      float* outc = Cp + ((size_t)(b * 96 + nn)) * LSEQ + l0;
      #pragma unroll
      for (int j = 0; j < 16; j += 4) {
        float4 v;
        v.x = Tr[(q * 16 + j    ) * 65 + n] + bj;
        v.y = Tr[(q * 16 + j + 1) * 65 + n] + bj;
        v.z = Tr[(q * 16 + j + 2) * 65 + n] + bj;
        v.w = Tr[(q * 16 + j + 3) * 65 + n] + bj;
        *(float4*)&outc[j] = v;
      }
    }
  }
}

// ---------------- causal depthwise conv1d (K=4) + silu, f32, float2 over e --
__global__ void conv1d_kernel(const float* __restrict__ xz, const float* __restrict__ cw,
                              const float* __restrict__ cb, float* __restrict__ xc) {
  int dir = blockIdx.y;
  int idx = blockIdx.x * 256 + threadIdx.x;   // 16000*96
  int e2 = idx % 96;
  int m = idx / 96;
  int b = m / LSEQ, s = m % LSEQ;
  int e = e2 * 2;
  const float* w = cw + dir * EC * 4 + e * 4;
  float2 acc = make_float2(cb[dir * EC + e], cb[dir * EC + e + 1]);
  #pragma unroll
  for (int k = 0; k < 4; ++k) {
    int sp = s - 3 + k;
    if (sp >= 0) {
      int p = dir ? (LSEQ - 1 - sp) : sp;
      float2 v = *(const float2*)&xz[((size_t)(b * LSEQ + p)) * 384 + e];
      acc.x = fmaf(w[k], v.x, acc.x);
      acc.y = fmaf(w[4 + k], v.y, acc.y);
    }
  }
  float2 r = make_float2(siluf(acc.x), siluf(acc.y));
  *(float2*)&xc[(size_t)dir * BLEc + (size_t)m * EC + e] = r;
}

// ---------------- chunked selective scan, e-parallel, dt fused ---------------
// pass1: block=(c,b,dir), thread=e; local scan (h_in=0) -> P, hend.
__global__ void scan_pass1(const float* __restrict__ xc, const float* __restrict__ dbl,
                           const float* __restrict__ A_log, const float* __restrict__ dtw,
                           const float* __restrict__ dtb,
                           float* __restrict__ Pm, float* __restrict__ hend) {
  int c = blockIdx.x, b = blockIdx.y, dir = blockIdx.z;
  int e = threadIdx.x;    // 192
  __shared__ float Ds[CHL][40];
  const float* xcp = xc + (size_t)dir * BLEc;
  const float* dblp = dbl + (size_t)dir * BL38c;
  size_t base38 = (size_t)(b * LSEQ + c * CHL) * 38;
  for (int i = e; i < CHL * 38; i += 192) Ds[i / 38][i % 38] = dblp[base38 + i];
  __syncthreads();
  float w6[6], Areg[16], h[16], P[16];
  const float* dtwp = dtw + (dir * EC + e) * 6;
  #pragma unroll
  for (int r = 0; r < 6; ++r) w6[r] = dtwp[r];
  float dtbv = dtb[dir * EC + e];
  #pragma unroll
  for (int n = 0; n < 16; ++n) {
    Areg[n] = -__expf(A_log[(dir * EC + e) * 16 + n]);
    h[n] = 0.f; P[n] = 1.f;
  }
  int rbase = b * LSEQ + c * CHL;
  for (int s = 0; s < CHL; ++s) {
    float dtr = dtbv;
    #pragma unroll
    for (int r = 0; r < 6; ++r) dtr = fmaf(Ds[s][r], w6[r], dtr);
    float dtv = softplusf(dtr);
    float xcv = xcp[(size_t)(rbase + s) * EC + e];
    float dx = dtv * xcv;
    #pragma unroll
    for (int n = 0; n < 16; ++n) {
      float a = __expf(dtv * Areg[n]);
      P[n] *= a;
      h[n] = fmaf(h[n], a, Ds[s][6 + n] * dx);
    }
  }
  size_t sbase = (size_t)c * SUMW + ((size_t)(dir * 2 + b) * EC + e) * 16;
  #pragma unroll
  for (int n = 0; n < 16; ++n) { Pm[sbase + n] = P[n]; hend[sbase + n] = h[n]; }
}

__global__ void scan_pass2(const float* __restrict__ Pm, const float* __restrict__ hend,
                           float* __restrict__ carry) {
  int idx = blockIdx.x * 256 + threadIdx.x;   // SUMW
  if (idx >= SUMW) return;
  float H = 0.f;
  for (int c = 0; c < NCH; ++c) {
    size_t p = (size_t)c * SUMW + idx;
    carry[p] = H;
    H = H * Pm[p] + hend[p];
  }
}

// pass3: recompute with carry-in; y = sum_n C*h + xc*D, gate silu(z), un-reverse.
__global__ void scan_pass3(const float* __restrict__ xc, const float* __restrict__ dbl,
                           const float* __restrict__ carry, const float* __restrict__ A_log,
                           const float* __restrict__ dtw, const float* __restrict__ dtb,
                           const float* __restrict__ Dp, const float* __restrict__ xz,
                           float* __restrict__ ybuf) {
  int c = blockIdx.x, b = blockIdx.y, dir = blockIdx.z;
  int e = threadIdx.x;    // 192
  __shared__ float Ds[CHL][40];
  const float* xcp = xc + (size_t)dir * BLEc;
  const float* dblp = dbl + (size_t)dir * BL38c;
  size_t base38 = (size_t)(b * LSEQ + c * CHL) * 38;
  for (int i = e; i < CHL * 38; i += 192) Ds[i / 38][i % 38] = dblp[base38 + i];
  __syncthreads();
  float w6[6], Areg[16], h[16];
  const float* dtwp = dtw + (dir * EC + e) * 6;
  #pragma unroll
  for (int r = 0; r < 6; ++r) w6[r] = dtwp[r];
  float dtbv = dtb[dir * EC + e];
  size_t cbase = (size_t)c * SUMW + ((size_t)(dir * 2 + b) * EC + e) * 16;
  #pragma unroll
  for (int n = 0; n < 16; ++n) {
    Areg[n] = -__expf(A_log[(dir * EC + e) * 16 + n]);
    h[n] = carry[cbase + n];
  }
  float Dv = Dp[dir * EC + e];
  int rbase = b * LSEQ + c * CHL;
  for (int s = 0; s < CHL; ++s) {
    int gs = c * CHL + s;
    float dtr = dtbv;
    #pragma unroll
    for (int r = 0; r < 6; ++r) dtr = fmaf(Ds[s][r], w6[r], dtr);
    float dtv = softplusf(dtr);
    float xcv = xcp[(size_t)(rbase + s) * EC + e];
    float dx = dtv * xcv;
    float y = 0.f;
    #pragma unroll
    for (int n = 0; n < 16; ++n) {
      float a = __expf(dtv * Areg[n]);
      h[n] = fmaf(h[n], a, Ds[s][6 + n] * dx);
      y = fmaf(h[n], Ds[s][22 + n], y);
    }
    y = fmaf(xcv, Dv, y);
    int p = dir ? (LSEQ - 1 - gs) : gs;
    size_t prow = (size_t)(b * LSEQ + p);
    float zv = xz[prow * 384 + 192 + e];
    ybuf[(size_t)dir * BLEc + prow * EC + e] = y * siluf(zv);
  }
}

}  // namespace

extern "C" void kernel_launch(void* const* d_in, const int* in_sizes, int n_in,
                              void* d_out, int out_size, void* d_ws, size_t ws_size,
                              hipStream_t stream) {
  const float* x      = (const float*)d_in[0];
  const float* ds_w   = (const float*)d_in[1];
  const float* ds_b   = (const float*)d_in[2];
  const float* ds_ln_w= (const float*)d_in[3];
  const float* ds_ln_b= (const float*)d_in[4];
  const float* ln_w   = (const float*)d_in[5];
  const float* ln_b   = (const float*)d_in[6];
  const float* in_w   = (const float*)d_in[7];
  const float* conv_w = (const float*)d_in[8];
  const float* conv_b = (const float*)d_in[9];
  const float* xp_w   = (const float*)d_in[10];
  const float* dtp_w  = (const float*)d_in[11];
  const float* dtp_b  = (const float*)d_in[12];
  const float* A_log  = (const float*)d_in[13];
  const float* Dp     = (const float*)d_in[14];
  const float* out_w  = (const float*)d_in[15];
  const float* f_ln_w = (const float*)d_in[16];
  const float* f_ln_b = (const float*)d_in[17];
  const float* fc1_w  = (const float*)d_in[18];
  const float* fc1_b  = (const float*)d_in[19];
  const float* fc2_w  = (const float*)d_in[20];
  const float* fc2_b  = (const float*)d_in[21];
  float* outp = (float*)d_out;
  float* ws = (float*)d_ws;

  size_t o = 0;
  float* xa   = ws + o;  o += 1536000;              // ds-conv out (f32)
  float* xf   = ws + o;  o += 1536000;              // residual stream (f32)
  float* xn   = ws + o;  o += 1536000;              // LN out (f32) 16000x96
  float* xz   = ws + o;  o += 6144000;              // in-proj / fc1 out (f32) 16000x384
  float* xcb  = ws + o;  o += 2 * (size_t)BLEc;     // conv out (f32)
  float* dblb = ws + o;  o += 2 * (size_t)BL38c;    // x-proj out (f32)
  float* ybuf = ws + o;  o += 2 * (size_t)BLEc;     // scan out (f32)
  float* Pm   = ws + o;  o += (size_t)NCH * SUMW;
  float* hend = ws + o;  o += (size_t)NCH * SUMW;
  float* carry= ws + o;  o += (size_t)NCH * SUMW;

  // Stage A: ds-conv as im2col split-bf16 MFMA GEMM (M=16000,N=96,K=384) -> LN.
  gemm_mfma<0, 0, 2><<<dim3(250, 2), 256, 0, stream>>>(
      x, nullptr, ds_w, ds_b, xa, MROWS, 96, 384, 96, 0, 0, 0);
  ln_row_kernel<<<4000, 256, 0, stream>>>(xa, ds_ln_w, ds_ln_b, xf, 1e-6f);

  for (int i = 0; i < 2; ++i) {
    ln_row_kernel<<<4000, 256, 0, stream>>>(xf, ln_w + i * 96, ln_b + i * 96, xn, 1e-5f);
    gemm_mfma<0, 0, 0><<<dim3(250, 6), 256, 0, stream>>>(
        xn, nullptr, in_w + (size_t)i * 384 * 96, nullptr, xz, MROWS, 384, 96, 384, 0, 0, 0);
    conv1d_kernel<<<dim3(6000, 2), 256, 0, stream>>>(
        xz, conv_w + (size_t)i * 2 * EC * 4, conv_b + (size_t)i * 2 * EC, xcb);
    gemm_mfma<0, 0, 0><<<dim3(250, 1, 2), 256, 0, stream>>>(
        xcb, nullptr, xp_w + (size_t)i * 2 * 38 * EC, nullptr, dblb,
        MROWS, 38, 192, 38, (size_t)BLEc, (size_t)38 * EC, (size_t)BL38c);
    scan_pass1<<<dim3(NCH, 2, 2), 192, 0, stream>>>(
        xcb, dblb, A_log + (size_t)i * 2 * EC * 16,
        dtp_w + (size_t)i * 2 * EC * 6, dtp_b + (size_t)i * 2 * EC, Pm, hend);
    scan_pass2<<<48, 256, 0, stream>>>(Pm, hend, carry);
    scan_pass3<<<dim3(NCH, 2, 2), 192, 0, stream>>>(
        xcb, dblb, carry, A_log + (size_t)i * 2 * EC * 16,
        dtp_w + (size_t)i * 2 * EC * 6, dtp_b + (size_t)i * 2 * EC,
        Dp + (size_t)i * 2 * EC, xz, ybuf);
    gemm_mfma<0, 0, 1><<<dim3(250, 2), 256, 0, stream>>>(
        ybuf, ybuf + BLEc, out_w + (size_t)i * 96 * EC, nullptr, xf,
        MROWS, 96, 192, 96, 0, 0, 0);
  }

  ln_row_kernel<<<4000, 256, 0, stream>>>(xf, f_ln_w, f_ln_b, xn, 1e-6f);
  gemm_mfma<1, 0, 0><<<dim3(250, 6), 256, 0, stream>>>(
      xn, nullptr, fc1_w, fc1_b, xz, MROWS, 384, 96, 384, 0, 0, 0);
  gemm_mfma<0, 1, 0><<<dim3(250, 2), 256, 0, stream>>>(
      xz, nullptr, fc2_w, fc2_b, outp, MROWS, 96, 384, 96, 0, 0, 0);
}

// Round 6
// 540.445 us; speedup vs baseline: 2.5849x; 1.1567x over previous
//
#include <hip/hip_runtime.h>
#include <hip/hip_bf16.h>
#include <math.h>

namespace {

constexpr int LSEQ  = 8000;
constexpr int MROWS = 16000;          // 2 * 8000
constexpr int EC    = 192;
constexpr int NCH   = 250;            // chunks per sequence
constexpr int CHL   = 32;             // chunk length (250*32 = 8000)
constexpr int BLEc  = MROWS * EC;     // 3,072,000
constexpr int BL38c = MROWS * 38;     // 608,000
constexpr int SUMW  = 2 * 2 * EC * 16;  // 12288 scan lanes

typedef __attribute__((ext_vector_type(8))) short bf16x8;
typedef __attribute__((ext_vector_type(4))) float f32x4;

__device__ __forceinline__ float siluf(float x) { return x / (1.f + __expf(-x)); }
__device__ __forceinline__ float softplusf(float x) {
  if (x > 20.f) return x;
  return log1pf(__expf(x));
}
__device__ __forceinline__ short f2bf(float f) {
  __hip_bfloat16 h = __float2bfloat16(f);
  return *reinterpret_cast<short*>(&h);
}
__device__ __forceinline__ float bf2f(short s) {
  __hip_bfloat16 h;
  *reinterpret_cast<short*>(&h) = s;
  return __bfloat162float(h);
}
// split fp32 -> (hi, lo) bf16 pair: x ~= hi + lo with ~2^-17 representation err
__device__ __forceinline__ void splitbf(float x, short& hi, short& lo) {
  hi = f2bf(x);
  lo = f2bf(x - bf2f(hi));
}

// ---------------- row LN over last dim 96 (wave per row), f32 out ------------
__global__ void ln_row_kernel(const float* __restrict__ in, const float* __restrict__ w,
                              const float* __restrict__ bv, float* __restrict__ out, float eps) {
  int lane = threadIdx.x & 63;
  int row = blockIdx.x * 4 + (threadIdx.x >> 6);   // 4000 blocks * 4 = 16000
  const float* r = in + (size_t)row * 96;
  float v0 = r[lane];
  float v1 = (lane < 32) ? r[64 + lane] : 0.f;
  float s = v0 + v1, s2 = v0 * v0 + v1 * v1;
  #pragma unroll
  for (int o = 32; o; o >>= 1) { s += __shfl_xor(s, o); s2 += __shfl_xor(s2, o); }
  float m = s * (1.f / 96.f);
  float var = s2 * (1.f / 96.f) - m * m;
  float rs = rsqrtf(var + eps);
  float* orow = out + (size_t)row * 96;
  orow[lane] = (v0 - m) * rs * w[lane] + bv[lane];
  if (lane < 32) orow[64 + lane] = (v1 - m) * rs * w[64 + lane] + bv[64 + lane];
}

// ---------------- split-bf16 MFMA GEMM: C[m,n] = act(sum_k A[m,k]W[n,k]+bias) --
// A, W fp32 in memory; staged as (hi,lo) bf16 pairs; 3 MFMAs per fragment pair.
// Tile 64x64, BK=128, 256 threads (4 waves = 2x2 quadrants of 32x32).
// AMODE: 0 A fp32 [M][Kk]; 2 im2col from x (2,48,40,40,40);
//        3 (A+A2)*silu(Z[m,192+k]) gated sum (out-proj; Z rows stride 384).
// ACT: 0 none, 1 exact gelu.  OUTM: 0 row-major f32 (ldc); 1 transpose (b,n,l) f32.
template<int ACT, int OUTM, int AMODE>
__global__ __launch_bounds__(256) void gemm_mfma(
    const float* __restrict__ A, const float* __restrict__ A2,
    const float* __restrict__ Zp, const float* __restrict__ W,
    const float* __restrict__ bias, float* __restrict__ Cp,
    int M, int Nn, int Kk, int ldc,
    size_t aStride, size_t wStride, size_t cStride) {
  __shared__ short Al[2][64][136];   // [hi/lo][row][k], row stride 272B
  __shared__ short Bl[2][64][136];
  int tid = threadIdx.x;
  int lane = tid & 63, wid = tid >> 6;
  int wr = wid >> 1, wc = wid & 1;
  int bm = blockIdx.x, bn = blockIdx.y;
  int m0 = bm * 64;
  A += aStride * blockIdx.z;
  if (AMODE == 3) A2 += aStride * blockIdx.z;
  W += wStride * blockIdx.z;
  Cp += cStride * blockIdx.z;
  f32x4 acc[2][2] = {};
  for (int k0 = 0; k0 < Kk; k0 += 128) {
    int Kcur = Kk - k0; if (Kcur > 128) Kcur = 128;
    // ---- stage A ----
    if (AMODE == 2) {
      #pragma unroll
      for (int i = tid; i < 64 * 64; i += 256) {
        int p = i & 3, c16 = (i >> 2) & 15, r = i >> 6;
        int m = m0 + r;
        int b = m / 8000, l = m % 8000;
        int dd = l / 400, hh = (l / 20) % 20, wd = l % 20;
        int off = (p >> 1) * 1600 + (p & 1) * 40;
        const float* xp = A + ((size_t)b * 48 + (k0 >> 3) + c16) * 64000
                            + dd * 3200 + hh * 80 + wd * 2 + off;
        float2 v = *(const float2*)xp;
        int k = c16 * 8 + p * 2;
        splitbf(v.x, Al[0][r][k], Al[1][r][k]);
        splitbf(v.y, Al[0][r][k + 1], Al[1][r][k + 1]);
      }
    } else {
      #pragma unroll
      for (int i = tid; i < 64 * 16; i += 256) {
        int kq = i & 15, r = i >> 4;
        if (kq * 8 < Kcur) {
          const float* ap = A + (size_t)(m0 + r) * Kk + k0 + kq * 8;
          float4 v0 = *(const float4*)ap;
          float4 v1 = *(const float4*)(ap + 4);
          if (AMODE == 3) {
            const float* bp = A2 + (size_t)(m0 + r) * Kk + k0 + kq * 8;
            float4 u0 = *(const float4*)bp;
            float4 u1 = *(const float4*)(bp + 4);
            const float* zp = Zp + (size_t)(m0 + r) * 384 + 192 + k0 + kq * 8;
            float4 z0 = *(const float4*)zp;
            float4 z1 = *(const float4*)(zp + 4);
            v0.x = (v0.x + u0.x) * siluf(z0.x);
            v0.y = (v0.y + u0.y) * siluf(z0.y);
            v0.z = (v0.z + u0.z) * siluf(z0.z);
            v0.w = (v0.w + u0.w) * siluf(z0.w);
            v1.x = (v1.x + u1.x) * siluf(z1.x);
            v1.y = (v1.y + u1.y) * siluf(z1.y);
            v1.z = (v1.z + u1.z) * siluf(z1.z);
            v1.w = (v1.w + u1.w) * siluf(z1.w);
          }
          float vals[8] = {v0.x, v0.y, v0.z, v0.w, v1.x, v1.y, v1.z, v1.w};
          bf16x8 hi, lo;
          #pragma unroll
          for (int j = 0; j < 8; ++j) { short h, l2; splitbf(vals[j], h, l2); hi[j] = h; lo[j] = l2; }
          *(bf16x8*)&Al[0][r][kq * 8] = hi;
          *(bf16x8*)&Al[1][r][kq * 8] = lo;
        }
      }
    }
    // ---- stage W ----
    #pragma unroll
    for (int i = tid; i < 64 * 16; i += 256) {
      int kq = i & 15, nr = i >> 4;
      if (kq * 8 < Kcur) {
        int n = bn * 64 + nr;
        bf16x8 hi = {0,0,0,0,0,0,0,0}, lo = {0,0,0,0,0,0,0,0};
        if (n < Nn) {
          const float* wp = &W[(size_t)n * Kk + k0 + kq * 8];
          float4 w0 = *(const float4*)wp;
          float4 w1 = *(const float4*)(wp + 4);
          float vals[8] = {w0.x, w0.y, w0.z, w0.w, w1.x, w1.y, w1.z, w1.w};
          #pragma unroll
          for (int j = 0; j < 8; ++j) { short h, l2; splitbf(vals[j], h, l2); hi[j] = h; lo[j] = l2; }
        }
        *(bf16x8*)&Bl[0][nr][kq * 8] = hi;
        *(bf16x8*)&Bl[1][nr][kq * 8] = lo;
      }
    }
    __syncthreads();
    int mr = lane & 15;
    int kq0 = (lane >> 4) * 8;
    #pragma unroll
    for (int ks = 0; ks < 4; ++ks) {
      if (ks * 32 >= Kcur) break;
      int kb = ks * 32 + kq0;
      bf16x8 a0h = *(const bf16x8*)&Al[0][wr * 32 + mr][kb];
      bf16x8 a0l = *(const bf16x8*)&Al[1][wr * 32 + mr][kb];
      bf16x8 a1h = *(const bf16x8*)&Al[0][wr * 32 + 16 + mr][kb];
      bf16x8 a1l = *(const bf16x8*)&Al[1][wr * 32 + 16 + mr][kb];
      bf16x8 b0h = *(const bf16x8*)&Bl[0][wc * 32 + mr][kb];
      bf16x8 b0l = *(const bf16x8*)&Bl[1][wc * 32 + mr][kb];
      bf16x8 b1h = *(const bf16x8*)&Bl[0][wc * 32 + 16 + mr][kb];
      bf16x8 b1l = *(const bf16x8*)&Bl[1][wc * 32 + 16 + mr][kb];
      acc[0][0] = __builtin_amdgcn_mfma_f32_16x16x32_bf16(a0h, b0h, acc[0][0], 0, 0, 0);
      acc[0][0] = __builtin_amdgcn_mfma_f32_16x16x32_bf16(a0h, b0l, acc[0][0], 0, 0, 0);
      acc[0][0] = __builtin_amdgcn_mfma_f32_16x16x32_bf16(a0l, b0h, acc[0][0], 0, 0, 0);
      acc[0][1] = __builtin_amdgcn_mfma_f32_16x16x32_bf16(a0h, b1h, acc[0][1], 0, 0, 0);
      acc[0][1] = __builtin_amdgcn_mfma_f32_16x16x32_bf16(a0h, b1l, acc[0][1], 0, 0, 0);
      acc[0][1] = __builtin_amdgcn_mfma_f32_16x16x32_bf16(a0l, b1h, acc[0][1], 0, 0, 0);
      acc[1][0] = __builtin_amdgcn_mfma_f32_16x16x32_bf16(a1h, b0h, acc[1][0], 0, 0, 0);
      acc[1][0] = __builtin_amdgcn_mfma_f32_16x16x32_bf16(a1h, b0l, acc[1][0], 0, 0, 0);
      acc[1][0] = __builtin_amdgcn_mfma_f32_16x16x32_bf16(a1l, b0h, acc[1][0], 0, 0, 0);
      acc[1][1] = __builtin_amdgcn_mfma_f32_16x16x32_bf16(a1h, b1h, acc[1][1], 0, 0, 0);
      acc[1][1] = __builtin_amdgcn_mfma_f32_16x16x32_bf16(a1h, b1l, acc[1][1], 0, 0, 0);
      acc[1][1] = __builtin_amdgcn_mfma_f32_16x16x32_bf16(a1l, b1h, acc[1][1], 0, 0, 0);
    }
    __syncthreads();
  }
  // ---- epilogue ----
  if (OUTM == 0) {
    #pragma unroll
    for (int fm = 0; fm < 2; ++fm) {
      #pragma unroll
      for (int fn = 0; fn < 2; ++fn) {
        int nn = bn * 64 + wc * 32 + fn * 16 + (lane & 15);
        if (nn >= Nn) continue;
        float bj = bias ? bias[nn] : 0.f;
        #pragma unroll
        for (int r = 0; r < 4; ++r) {
          int mm = m0 + wr * 32 + fm * 16 + (lane >> 4) * 4 + r;
          float v = acc[fm][fn][r] + bj;
          if (ACT == 1) v = 0.5f * v * (1.f + erff(v * 0.70710678118f));
          Cp[(size_t)mm * ldc + nn] = v;
        }
      }
    }
  } else {
    // transpose 64x64 tile via LDS (overlay on Al)
    float* Tr = (float*)&Al[0][0][0];
    #pragma unroll
    for (int fm = 0; fm < 2; ++fm)
      #pragma unroll
      for (int fn = 0; fn < 2; ++fn)
        #pragma unroll
        for (int r = 0; r < 4; ++r) {
          int ml = wr * 32 + fm * 16 + (lane >> 4) * 4 + r;
          int nl = wc * 32 + fn * 16 + (lane & 15);
          Tr[ml * 65 + nl] = acc[fm][fn][r];
        }
    __syncthreads();
    int n = tid & 63, q = tid >> 6;
    int nn = bn * 64 + n;
    if (nn < Nn) {
      float bj = bias ? bias[nn] : 0.f;
      int b = m0 / LSEQ;
      int l0 = m0 % LSEQ + q * 16;
      float* outc = Cp + ((size_t)(b * 96 + nn)) * LSEQ + l0;
      #pragma unroll
      for (int j = 0; j < 16; j += 4) {
        float4 v;
        v.x = Tr[(q * 16 + j    ) * 65 + n] + bj;
        v.y = Tr[(q * 16 + j + 1) * 65 + n] + bj;
        v.z = Tr[(q * 16 + j + 2) * 65 + n] + bj;
        v.w = Tr[(q * 16 + j + 3) * 65 + n] + bj;
        *(float4*)&outc[j] = v;
      }
    }
  }
}

// ---------------- causal depthwise conv1d (K=4) + silu, f32, float2 over e --
__global__ void conv1d_kernel(const float* __restrict__ xz, const float* __restrict__ cw,
                              const float* __restrict__ cb, float* __restrict__ xc) {
  int dir = blockIdx.y;
  int idx = blockIdx.x * 256 + threadIdx.x;   // 16000*96
  int e2 = idx % 96;
  int m = idx / 96;
  int b = m / LSEQ, s = m % LSEQ;
  int e = e2 * 2;
  const float* w = cw + dir * EC * 4 + e * 4;
  float2 acc = make_float2(cb[dir * EC + e], cb[dir * EC + e + 1]);
  #pragma unroll
  for (int k = 0; k < 4; ++k) {
    int sp = s - 3 + k;
    if (sp >= 0) {
      int p = dir ? (LSEQ - 1 - sp) : sp;
      float2 v = *(const float2*)&xz[((size_t)(b * LSEQ + p)) * 384 + e];
      acc.x = fmaf(w[k], v.x, acc.x);
      acc.y = fmaf(w[4 + k], v.y, acc.y);
    }
  }
  float2 r = make_float2(siluf(acc.x), siluf(acc.y));
  *(float2*)&xc[(size_t)dir * BLEc + (size_t)m * EC + e] = r;
}

// ---------------- chunked selective scan, e-parallel, dt fused, LDS-staged ---
// pass1: block=(c,b,dir), thread=e; stage xc-chunk + dbl-chunk in LDS;
//        local scan (h_in=0) -> float2 (P, hend) summary per (lane, chunk).
__global__ void scan_pass1(const float* __restrict__ xc, const float* __restrict__ dbl,
                           const float* __restrict__ A_log, const float* __restrict__ dtw,
                           const float* __restrict__ dtb, float2* __restrict__ sumb) {
  int c = blockIdx.x, b = blockIdx.y, dir = blockIdx.z;
  int e = threadIdx.x;    // 192
  __shared__ float Ds[CHL][40];
  __shared__ float Xs[CHL][192];
  const float* xcp = xc + (size_t)dir * BLEc;
  const float* dblp = dbl + (size_t)dir * BL38c;
  int rbase = b * LSEQ + c * CHL;
  size_t base38 = (size_t)rbase * 38;
  for (int i = e; i < CHL * 38; i += 192) Ds[i / 38][i % 38] = dblp[base38 + i];
  #pragma unroll 4
  for (int s = 0; s < CHL; ++s) Xs[s][e] = xcp[(size_t)(rbase + s) * EC + e];
  __syncthreads();
  float w6[6], Areg[16], h[16], P[16];
  const float* dtwp = dtw + (dir * EC + e) * 6;
  #pragma unroll
  for (int r = 0; r < 6; ++r) w6[r] = dtwp[r];
  float dtbv = dtb[dir * EC + e];
  #pragma unroll
  for (int n = 0; n < 16; ++n) {
    Areg[n] = -__expf(A_log[(dir * EC + e) * 16 + n]);
    h[n] = 0.f; P[n] = 1.f;
  }
  for (int s = 0; s < CHL; ++s) {
    float dtr = dtbv;
    #pragma unroll
    for (int r = 0; r < 6; ++r) dtr = fmaf(Ds[s][r], w6[r], dtr);
    float dtv = softplusf(dtr);
    float dx = dtv * Xs[s][e];
    #pragma unroll
    for (int n = 0; n < 16; ++n) {
      float a = __expf(dtv * Areg[n]);
      P[n] *= a;
      h[n] = fmaf(h[n], a, Ds[s][6 + n] * dx);
    }
  }
  size_t sbase = (size_t)c * SUMW + ((size_t)(dir * 2 + b) * EC + e) * 16;
  #pragma unroll
  for (int n = 0; n < 16; ++n) sumb[sbase + n] = make_float2(P[n], h[n]);
}

// pass2: thread per scan-lane; batch-25 loads to hide latency; carry written
// in-place over the .x slot of sumb.
__global__ void scan_pass2(float2* __restrict__ sumb) {
  int idx = blockIdx.x * 256 + threadIdx.x;   // SUMW
  if (idx >= SUMW) return;
  float* sf = (float*)sumb;
  float H = 0.f;
  for (int c0 = 0; c0 < NCH; c0 += 25) {
    float2 pv[25];
    #pragma unroll
    for (int j = 0; j < 25; ++j) pv[j] = sumb[(size_t)(c0 + j) * SUMW + idx];
    #pragma unroll
    for (int j = 0; j < 25; ++j) {
      sf[2 * ((size_t)(c0 + j) * SUMW + idx)] = H;
      H = fmaf(H, pv[j].x, pv[j].y);
    }
  }
}

// pass3: recompute with carry-in; y = sum_n C*h + xc*D (NO gate), un-reverse.
__global__ void scan_pass3(const float* __restrict__ xc, const float* __restrict__ dbl,
                           const float2* __restrict__ sumb, const float* __restrict__ A_log,
                           const float* __restrict__ dtw, const float* __restrict__ dtb,
                           const float* __restrict__ Dp, float* __restrict__ ybuf) {
  int c = blockIdx.x, b = blockIdx.y, dir = blockIdx.z;
  int e = threadIdx.x;    // 192
  __shared__ float Ds[CHL][40];
  __shared__ float Xs[CHL][192];
  const float* xcp = xc + (size_t)dir * BLEc;
  const float* dblp = dbl + (size_t)dir * BL38c;
  int rbase = b * LSEQ + c * CHL;
  size_t base38 = (size_t)rbase * 38;
  for (int i = e; i < CHL * 38; i += 192) Ds[i / 38][i % 38] = dblp[base38 + i];
  #pragma unroll 4
  for (int s = 0; s < CHL; ++s) Xs[s][e] = xcp[(size_t)(rbase + s) * EC + e];
  __syncthreads();
  float w6[6], Areg[16], h[16];
  const float* dtwp = dtw + (dir * EC + e) * 6;
  #pragma unroll
  for (int r = 0; r < 6; ++r) w6[r] = dtwp[r];
  float dtbv = dtb[dir * EC + e];
  const float* sf = (const float*)sumb;
  size_t cbase = (size_t)c * SUMW + ((size_t)(dir * 2 + b) * EC + e) * 16;
  #pragma unroll
  for (int n = 0; n < 16; ++n) {
    Areg[n] = -__expf(A_log[(dir * EC + e) * 16 + n]);
    h[n] = sf[2 * (cbase + n)];
  }
  float Dv = Dp[dir * EC + e];
  for (int s = 0; s < CHL; ++s) {
    int gs = c * CHL + s;
    float dtr = dtbv;
    #pragma unroll
    for (int r = 0; r < 6; ++r) dtr = fmaf(Ds[s][r], w6[r], dtr);
    float dtv = softplusf(dtr);
    float xcv = Xs[s][e];
    float dx = dtv * xcv;
    float y = 0.f;
    #pragma unroll
    for (int n = 0; n < 16; ++n) {
      float a = __expf(dtv * Areg[n]);
      h[n] = fmaf(h[n], a, Ds[s][6 + n] * dx);
      y = fmaf(h[n], Ds[s][22 + n], y);
    }
    y = fmaf(xcv, Dv, y);
    int p = dir ? (LSEQ - 1 - gs) : gs;
    ybuf[(size_t)dir * BLEc + (size_t)(b * LSEQ + p) * EC + e] = y;
  }
}

}  // namespace

extern "C" void kernel_launch(void* const* d_in, const int* in_sizes, int n_in,
                              void* d_out, int out_size, void* d_ws, size_t ws_size,
                              hipStream_t stream) {
  const float* x      = (const float*)d_in[0];
  const float* ds_w   = (const float*)d_in[1];
  const float* ds_b   = (const float*)d_in[2];
  const float* ds_ln_w= (const float*)d_in[3];
  const float* ds_ln_b= (const float*)d_in[4];
  const float* ln_w   = (const float*)d_in[5];
  const float* ln_b   = (const float*)d_in[6];
  const float* in_w   = (const float*)d_in[7];
  const float* conv_w = (const float*)d_in[8];
  const float* conv_b = (const float*)d_in[9];
  const float* xp_w   = (const float*)d_in[10];
  const float* dtp_w  = (const float*)d_in[11];
  const float* dtp_b  = (const float*)d_in[12];
  const float* A_log  = (const float*)d_in[13];
  const float* Dp     = (const float*)d_in[14];
  const float* out_w  = (const float*)d_in[15];
  const float* f_ln_w = (const float*)d_in[16];
  const float* f_ln_b = (const float*)d_in[17];
  const float* fc1_w  = (const float*)d_in[18];
  const float* fc1_b  = (const float*)d_in[19];
  const float* fc2_w  = (const float*)d_in[20];
  const float* fc2_b  = (const float*)d_in[21];
  float* outp = (float*)d_out;
  float* ws = (float*)d_ws;

  size_t o = 0;
  float* xf   = ws + o;  o += 1536000;              // residual stream (f32)
  float* xn   = ws + o;  o += 1536000;              // LN out (f32)
  float* xz   = ws + o;  o += 6144000;              // in-proj / fc1 out (f32)
  float* xcb  = ws + o;  o += 2 * (size_t)BLEc;     // conv out (f32)
  float* dblb = ws + o;  o += 2 * (size_t)BL38c;    // x-proj out (f32)
  float* ybuf = ws + o;  o += 2 * (size_t)BLEc;     // scan out raw (f32)
  float2* sumb= (float2*)(ws + o); o += 2 * (size_t)NCH * SUMW;  // (P,h) per chunk
  float* xa   = ybuf;   // ds-conv out: dead before pass3 first writes ybuf

  // Stage A: ds-conv as im2col split-bf16 MFMA GEMM (M=16000,N=96,K=384) -> LN.
  gemm_mfma<0, 0, 2><<<dim3(250, 2), 256, 0, stream>>>(
      x, nullptr, nullptr, ds_w, ds_b, xa, MROWS, 96, 384, 96, 0, 0, 0);
  ln_row_kernel<<<4000, 256, 0, stream>>>(xa, ds_ln_w, ds_ln_b, xf, 1e-6f);

  for (int i = 0; i < 2; ++i) {
    ln_row_kernel<<<4000, 256, 0, stream>>>(xf, ln_w + i * 96, ln_b + i * 96, xn, 1e-5f);
    gemm_mfma<0, 0, 0><<<dim3(250, 6), 256, 0, stream>>>(
        xn, nullptr, nullptr, in_w + (size_t)i * 384 * 96, nullptr, xz,
        MROWS, 384, 96, 384, 0, 0, 0);
    conv1d_kernel<<<dim3(6000, 2), 256, 0, stream>>>(
        xz, conv_w + (size_t)i * 2 * EC * 4, conv_b + (size_t)i * 2 * EC, xcb);
    gemm_mfma<0, 0, 0><<<dim3(250, 1, 2), 256, 0, stream>>>(
        xcb, nullptr, nullptr, xp_w + (size_t)i * 2 * 38 * EC, nullptr, dblb,
        MROWS, 38, 192, 38, (size_t)BLEc, (size_t)38 * EC, (size_t)BL38c);
    scan_pass1<<<dim3(NCH, 2, 2), 192, 0, stream>>>(
        xcb, dblb, A_log + (size_t)i * 2 * EC * 16,
        dtp_w + (size_t)i * 2 * EC * 6, dtp_b + (size_t)i * 2 * EC, sumb);
    scan_pass2<<<48, 256, 0, stream>>>(sumb);
    scan_pass3<<<dim3(NCH, 2, 2), 192, 0, stream>>>(
        xcb, dblb, sumb, A_log + (size_t)i * 2 * EC * 16,
        dtp_w + (size_t)i * 2 * EC * 6, dtp_b + (size_t)i * 2 * EC,
        Dp + (size_t)i * 2 * EC, ybuf);
    gemm_mfma<0, 0, 3><<<dim3(250, 2), 256, 0, stream>>>(
        ybuf, ybuf + BLEc, xz, out_w + (size_t)i * 96 * EC, nullptr, xf,
        MROWS, 96, 192, 96, 0, 0, 0);
  }

  ln_row_kernel<<<4000, 256, 0, stream>>>(xf, f_ln_w, f_ln_b, xn, 1e-6f);
  gemm_mfma<1, 0, 0><<<dim3(250, 6), 256, 0, stream>>>(
      xn, nullptr, nullptr, fc1_w, fc1_b, xz, MROWS, 384, 96, 384, 0, 0, 0);
  gemm_mfma<0, 1, 0><<<dim3(250, 2), 256, 0, stream>>>(
      xz, nullptr, nullptr, fc2_w, fc2_b, outp, MROWS, 96, 384, 96, 0, 0, 0);
}

// Round 7
// 490.203 us; speedup vs baseline: 2.8499x; 1.1025x over previous
//
#include <hip/hip_runtime.h>
#include <hip/hip_bf16.h>
#include <math.h>

namespace {

constexpr int LSEQ  = 8000;
constexpr int MROWS = 16000;          // 2 * 8000
constexpr int EC    = 192;
constexpr int NCH   = 400;            // chunks per sequence
constexpr int CHL   = 20;             // chunk length (400*20 = 8000)
constexpr int BLEc  = MROWS * EC;     // 3,072,000
constexpr int BL38c = MROWS * 38;     // 608,000
constexpr int SUMW  = 2 * 2 * EC * 16;  // 12288 scan lanes

typedef __attribute__((ext_vector_type(8))) short bf16x8;
typedef __attribute__((ext_vector_type(4))) float f32x4;

__device__ __forceinline__ float siluf(float x) { return x / (1.f + __expf(-x)); }
__device__ __forceinline__ float softplusf(float x) {
  if (x > 20.f) return x;
  return __logf(1.f + __expf(x));
}
__device__ __forceinline__ short f2bf(float f) {
  __hip_bfloat16 h = __float2bfloat16(f);
  return *reinterpret_cast<short*>(&h);
}
__device__ __forceinline__ float bf2f(short s) {
  __hip_bfloat16 h;
  *reinterpret_cast<short*>(&h) = s;
  return __bfloat162float(h);
}
// split fp32 -> (hi, lo) bf16 pair: x ~= hi + lo with ~2^-17 representation err
__device__ __forceinline__ void splitbf(float x, short& hi, short& lo) {
  hi = f2bf(x);
  lo = f2bf(x - bf2f(hi));
}

// ---------------- row LN over last dim 96 (wave per row), f32 out ------------
__global__ void ln_row_kernel(const float* __restrict__ in, const float* __restrict__ w,
                              const float* __restrict__ bv, float* __restrict__ out, float eps) {
  int lane = threadIdx.x & 63;
  int row = blockIdx.x * 4 + (threadIdx.x >> 6);   // 4000 blocks * 4 = 16000
  const float* r = in + (size_t)row * 96;
  float v0 = r[lane];
  float v1 = (lane < 32) ? r[64 + lane] : 0.f;
  float s = v0 + v1, s2 = v0 * v0 + v1 * v1;
  #pragma unroll
  for (int o = 32; o; o >>= 1) { s += __shfl_xor(s, o); s2 += __shfl_xor(s2, o); }
  float m = s * (1.f / 96.f);
  float var = s2 * (1.f / 96.f) - m * m;
  float rs = rsqrtf(var + eps);
  float* orow = out + (size_t)row * 96;
  orow[lane] = (v0 - m) * rs * w[lane] + bv[lane];
  if (lane < 32) orow[64 + lane] = (v1 - m) * rs * w[64 + lane] + bv[64 + lane];
}

// ---------------- split-bf16 MFMA GEMM: C[m,n] = act(sum_k A[m,k]W[n,k]+bias) --
// A, W fp32 in memory; staged as (hi,lo) bf16 pairs; 3 MFMAs per fragment pair.
// Tile 64x64, BK=128, 256 threads (4 waves = 2x2 quadrants of 32x32).
// AMODE: 0 A fp32 [M][Kk]; 2 im2col from x (2,48,40,40,40);
//        3 (A+A2)*silu(Z[m,192+k]) gated sum (out-proj; Z rows stride 384).
// ACT: 0 none, 1 exact gelu.  OUTM: 0 row-major f32 (ldc); 1 transpose (b,n,l) f32.
template<int ACT, int OUTM, int AMODE>
__global__ __launch_bounds__(256) void gemm_mfma(
    const float* __restrict__ A, const float* __restrict__ A2,
    const float* __restrict__ Zp, const float* __restrict__ W,
    const float* __restrict__ bias, float* __restrict__ Cp,
    int M, int Nn, int Kk, int ldc,
    size_t aStride, size_t wStride, size_t cStride) {
  __shared__ short Al[2][64][136];   // [hi/lo][row][k], row stride 272B
  __shared__ short Bl[2][64][136];
  int tid = threadIdx.x;
  int lane = tid & 63, wid = tid >> 6;
  int wr = wid >> 1, wc = wid & 1;
  int bm = blockIdx.x, bn = blockIdx.y;
  int m0 = bm * 64;
  A += aStride * blockIdx.z;
  if (AMODE == 3) A2 += aStride * blockIdx.z;
  W += wStride * blockIdx.z;
  Cp += cStride * blockIdx.z;
  f32x4 acc[2][2] = {};
  for (int k0 = 0; k0 < Kk; k0 += 128) {
    int Kcur = Kk - k0; if (Kcur > 128) Kcur = 128;
    // ---- stage A ----
    if (AMODE == 2) {
      #pragma unroll
      for (int i = tid; i < 64 * 64; i += 256) {
        int p = i & 3, c16 = (i >> 2) & 15, r = i >> 6;
        int m = m0 + r;
        int b = m / 8000, l = m % 8000;
        int dd = l / 400, hh = (l / 20) % 20, wd = l % 20;
        int off = (p >> 1) * 1600 + (p & 1) * 40;
        const float* xp = A + ((size_t)b * 48 + (k0 >> 3) + c16) * 64000
                            + dd * 3200 + hh * 80 + wd * 2 + off;
        float2 v = *(const float2*)xp;
        int k = c16 * 8 + p * 2;
        splitbf(v.x, Al[0][r][k], Al[1][r][k]);
        splitbf(v.y, Al[0][r][k + 1], Al[1][r][k + 1]);
      }
    } else {
      #pragma unroll
      for (int i = tid; i < 64 * 16; i += 256) {
        int kq = i & 15, r = i >> 4;
        if (kq * 8 < Kcur) {
          const float* ap = A + (size_t)(m0 + r) * Kk + k0 + kq * 8;
          float4 v0 = *(const float4*)ap;
          float4 v1 = *(const float4*)(ap + 4);
          if (AMODE == 3) {
            const float* bp = A2 + (size_t)(m0 + r) * Kk + k0 + kq * 8;
            float4 u0 = *(const float4*)bp;
            float4 u1 = *(const float4*)(bp + 4);
            const float* zp = Zp + (size_t)(m0 + r) * 384 + 192 + k0 + kq * 8;
            float4 z0 = *(const float4*)zp;
            float4 z1 = *(const float4*)(zp + 4);
            v0.x = (v0.x + u0.x) * siluf(z0.x);
            v0.y = (v0.y + u0.y) * siluf(z0.y);
            v0.z = (v0.z + u0.z) * siluf(z0.z);
            v0.w = (v0.w + u0.w) * siluf(z0.w);
            v1.x = (v1.x + u1.x) * siluf(z1.x);
            v1.y = (v1.y + u1.y) * siluf(z1.y);
            v1.z = (v1.z + u1.z) * siluf(z1.z);
            v1.w = (v1.w + u1.w) * siluf(z1.w);
          }
          float vals[8] = {v0.x, v0.y, v0.z, v0.w, v1.x, v1.y, v1.z, v1.w};
          bf16x8 hi, lo;
          #pragma unroll
          for (int j = 0; j < 8; ++j) { short h, l2; splitbf(vals[j], h, l2); hi[j] = h; lo[j] = l2; }
          *(bf16x8*)&Al[0][r][kq * 8] = hi;
          *(bf16x8*)&Al[1][r][kq * 8] = lo;
        }
      }
    }
    // ---- stage W ----
    #pragma unroll
    for (int i = tid; i < 64 * 16; i += 256) {
      int kq = i & 15, nr = i >> 4;
      if (kq * 8 < Kcur) {
        int n = bn * 64 + nr;
        bf16x8 hi = {0,0,0,0,0,0,0,0}, lo = {0,0,0,0,0,0,0,0};
        if (n < Nn) {
          const float* wp = &W[(size_t)n * Kk + k0 + kq * 8];
          float4 w0 = *(const float4*)wp;
          float4 w1 = *(const float4*)(wp + 4);
          float vals[8] = {w0.x, w0.y, w0.z, w0.w, w1.x, w1.y, w1.z, w1.w};
          #pragma unroll
          for (int j = 0; j < 8; ++j) { short h, l2; splitbf(vals[j], h, l2); hi[j] = h; lo[j] = l2; }
        }
        *(bf16x8*)&Bl[0][nr][kq * 8] = hi;
        *(bf16x8*)&Bl[1][nr][kq * 8] = lo;
      }
    }
    __syncthreads();
    int mr = lane & 15;
    int kq0 = (lane >> 4) * 8;
    #pragma unroll
    for (int ks = 0; ks < 4; ++ks) {
      if (ks * 32 >= Kcur) break;
      int kb = ks * 32 + kq0;
      bf16x8 a0h = *(const bf16x8*)&Al[0][wr * 32 + mr][kb];
      bf16x8 a0l = *(const bf16x8*)&Al[1][wr * 32 + mr][kb];
      bf16x8 a1h = *(const bf16x8*)&Al[0][wr * 32 + 16 + mr][kb];
      bf16x8 a1l = *(const bf16x8*)&Al[1][wr * 32 + 16 + mr][kb];
      bf16x8 b0h = *(const bf16x8*)&Bl[0][wc * 32 + mr][kb];
      bf16x8 b0l = *(const bf16x8*)&Bl[1][wc * 32 + mr][kb];
      bf16x8 b1h = *(const bf16x8*)&Bl[0][wc * 32 + 16 + mr][kb];
      bf16x8 b1l = *(const bf16x8*)&Bl[1][wc * 32 + 16 + mr][kb];
      acc[0][0] = __builtin_amdgcn_mfma_f32_16x16x32_bf16(a0h, b0h, acc[0][0], 0, 0, 0);
      acc[0][0] = __builtin_amdgcn_mfma_f32_16x16x32_bf16(a0h, b0l, acc[0][0], 0, 0, 0);
      acc[0][0] = __builtin_amdgcn_mfma_f32_16x16x32_bf16(a0l, b0h, acc[0][0], 0, 0, 0);
      acc[0][1] = __builtin_amdgcn_mfma_f32_16x16x32_bf16(a0h, b1h, acc[0][1], 0, 0, 0);
      acc[0][1] = __builtin_amdgcn_mfma_f32_16x16x32_bf16(a0h, b1l, acc[0][1], 0, 0, 0);
      acc[0][1] = __builtin_amdgcn_mfma_f32_16x16x32_bf16(a0l, b1h, acc[0][1], 0, 0, 0);
      acc[1][0] = __builtin_amdgcn_mfma_f32_16x16x32_bf16(a1h, b0h, acc[1][0], 0, 0, 0);
      acc[1][0] = __builtin_amdgcn_mfma_f32_16x16x32_bf16(a1h, b0l, acc[1][0], 0, 0, 0);
      acc[1][0] = __builtin_amdgcn_mfma_f32_16x16x32_bf16(a1l, b0h, acc[1][0], 0, 0, 0);
      acc[1][1] = __builtin_amdgcn_mfma_f32_16x16x32_bf16(a1h, b1h, acc[1][1], 0, 0, 0);
      acc[1][1] = __builtin_amdgcn_mfma_f32_16x16x32_bf16(a1h, b1l, acc[1][1], 0, 0, 0);
      acc[1][1] = __builtin_amdgcn_mfma_f32_16x16x32_bf16(a1l, b1h, acc[1][1], 0, 0, 0);
    }
    __syncthreads();
  }
  // ---- epilogue ----
  if (OUTM == 0) {
    #pragma unroll
    for (int fm = 0; fm < 2; ++fm) {
      #pragma unroll
      for (int fn = 0; fn < 2; ++fn) {
        int nn = bn * 64 + wc * 32 + fn * 16 + (lane & 15);
        if (nn >= Nn) continue;
        float bj = bias ? bias[nn] : 0.f;
        #pragma unroll
        for (int r = 0; r < 4; ++r) {
          int mm = m0 + wr * 32 + fm * 16 + (lane >> 4) * 4 + r;
          float v = acc[fm][fn][r] + bj;
          if (ACT == 1) v = 0.5f * v * (1.f + erff(v * 0.70710678118f));
          Cp[(size_t)mm * ldc + nn] = v;
        }
      }
    }
  } else {
    // transpose 64x64 tile via LDS (overlay on Al)
    float* Tr = (float*)&Al[0][0][0];
    #pragma unroll
    for (int fm = 0; fm < 2; ++fm)
      #pragma unroll
      for (int fn = 0; fn < 2; ++fn)
        #pragma unroll
        for (int r = 0; r < 4; ++r) {
          int ml = wr * 32 + fm * 16 + (lane >> 4) * 4 + r;
          int nl = wc * 32 + fn * 16 + (lane & 15);
          Tr[ml * 65 + nl] = acc[fm][fn][r];
        }
    __syncthreads();
    int n = tid & 63, q = tid >> 6;
    int nn = bn * 64 + n;
    if (nn < Nn) {
      float bj = bias ? bias[nn] : 0.f;
      int b = m0 / LSEQ;
      int l0 = m0 % LSEQ + q * 16;
      float* outc = Cp + ((size_t)(b * 96 + nn)) * LSEQ + l0;
      #pragma unroll
      for (int j = 0; j < 16; j += 4) {
        float4 v;
        v.x = Tr[(q * 16 + j    ) * 65 + n] + bj;
        v.y = Tr[(q * 16 + j + 1) * 65 + n] + bj;
        v.z = Tr[(q * 16 + j + 2) * 65 + n] + bj;
        v.w = Tr[(q * 16 + j + 3) * 65 + n] + bj;
        *(float4*)&outc[j] = v;
      }
    }
  }
}

// ---------------- causal depthwise conv1d (K=4) + silu, f32, float2 over e --
__global__ void conv1d_kernel(const float* __restrict__ xz, const float* __restrict__ cw,
                              const float* __restrict__ cb, float* __restrict__ xc) {
  int dir = blockIdx.y;
  int idx = blockIdx.x * 256 + threadIdx.x;   // 16000*96
  int e2 = idx % 96;
  int m = idx / 96;
  int b = m / LSEQ, s = m % LSEQ;
  int e = e2 * 2;
  const float* w = cw + dir * EC * 4 + e * 4;
  float2 acc = make_float2(cb[dir * EC + e], cb[dir * EC + e + 1]);
  #pragma unroll
  for (int k = 0; k < 4; ++k) {
    int sp = s - 3 + k;
    if (sp >= 0) {
      int p = dir ? (LSEQ - 1 - sp) : sp;
      float2 v = *(const float2*)&xz[((size_t)(b * LSEQ + p)) * 384 + e];
      acc.x = fmaf(w[k], v.x, acc.x);
      acc.y = fmaf(w[4 + k], v.y, acc.y);
    }
  }
  float2 r = make_float2(siluf(acc.x), siluf(acc.y));
  *(float2*)&xc[(size_t)dir * BLEc + (size_t)m * EC + e] = r;
}

// ---------------- chunked selective scan, e-parallel, dt fused ---------------
// Per block: one (chunk, b, dir); thread = e. Ds (dbl rows) in LDS (3.2 KB);
// xc read direct from global with 2-step register prefetch; 2-step unrolled body.
__global__ void scan_pass1(const float* __restrict__ xc, const float* __restrict__ dbl,
                           const float* __restrict__ A_log, const float* __restrict__ dtw,
                           const float* __restrict__ dtb, float2* __restrict__ sumb) {
  int c = blockIdx.x, b = blockIdx.y, dir = blockIdx.z;
  int e = threadIdx.x;    // 192
  __shared__ float Ds[CHL][40];
  const float* dblp = dbl + (size_t)dir * BL38c;
  int rbase = b * LSEQ + c * CHL;
  size_t base38 = (size_t)rbase * 38;
  for (int i = e; i < CHL * 38; i += 192) Ds[i / 38][i % 38] = dblp[base38 + i];
  __syncthreads();
  float w6[6], Areg[16], h[16], P[16];
  const float* dtwp = dtw + (dir * EC + e) * 6;
  #pragma unroll
  for (int r = 0; r < 6; ++r) w6[r] = dtwp[r];
  float dtbv = dtb[dir * EC + e];
  #pragma unroll
  for (int n = 0; n < 16; ++n) {
    Areg[n] = -__expf(A_log[(dir * EC + e) * 16 + n]);
    h[n] = 0.f; P[n] = 1.f;
  }
  const float* xg = xc + (size_t)dir * BLEc + (size_t)rbase * EC + e;
  float x0 = xg[0], x1 = xg[EC];
  for (int s = 0; s < CHL; s += 2) {
    float xn0 = 0.f, xn1 = 0.f;
    if (s + 2 < CHL) { xn0 = xg[(size_t)(s + 2) * EC]; xn1 = xg[(size_t)(s + 3) * EC]; }
    float dtr0 = dtbv, dtr1 = dtbv;
    #pragma unroll
    for (int r = 0; r < 6; ++r) {
      dtr0 = fmaf(Ds[s][r], w6[r], dtr0);
      dtr1 = fmaf(Ds[s + 1][r], w6[r], dtr1);
    }
    float dtv0 = softplusf(dtr0);
    float dtv1 = softplusf(dtr1);
    float dx0 = dtv0 * x0, dx1 = dtv1 * x1;
    #pragma unroll
    for (int n = 0; n < 16; ++n) {
      float a0 = __expf(dtv0 * Areg[n]);
      float a1 = __expf(dtv1 * Areg[n]);
      h[n] = fmaf(h[n], a0, Ds[s][6 + n] * dx0);
      h[n] = fmaf(h[n], a1, Ds[s + 1][6 + n] * dx1);
      P[n] *= a0 * a1;
    }
    x0 = xn0; x1 = xn1;
  }
  size_t sbase = (size_t)c * SUMW + ((size_t)(dir * 2 + b) * EC + e) * 16;
  #pragma unroll
  for (int n = 0; n < 16; ++n) sumb[sbase + n] = make_float2(P[n], h[n]);
}

// pass2: thread per scan-lane; batch-25 loads to hide latency; carry written
// in-place over the .x slot of sumb.
__global__ void scan_pass2(float2* __restrict__ sumb) {
  int idx = blockIdx.x * 256 + threadIdx.x;   // SUMW
  if (idx >= SUMW) return;
  float* sf = (float*)sumb;
  float H = 0.f;
  for (int c0 = 0; c0 < NCH; c0 += 25) {
    float2 pv[25];
    #pragma unroll
    for (int j = 0; j < 25; ++j) pv[j] = sumb[(size_t)(c0 + j) * SUMW + idx];
    #pragma unroll
    for (int j = 0; j < 25; ++j) {
      sf[2 * ((size_t)(c0 + j) * SUMW + idx)] = H;
      H = fmaf(H, pv[j].x, pv[j].y);
    }
  }
}

// pass3: recompute with carry-in; y = sum_n C*h + xc*D (NO gate), un-reverse.
__global__ void scan_pass3(const float* __restrict__ xc, const float* __restrict__ dbl,
                           const float2* __restrict__ sumb, const float* __restrict__ A_log,
                           const float* __restrict__ dtw, const float* __restrict__ dtb,
                           const float* __restrict__ Dp, float* __restrict__ ybuf) {
  int c = blockIdx.x, b = blockIdx.y, dir = blockIdx.z;
  int e = threadIdx.x;    // 192
  __shared__ float Ds[CHL][40];
  const float* dblp = dbl + (size_t)dir * BL38c;
  int rbase = b * LSEQ + c * CHL;
  size_t base38 = (size_t)rbase * 38;
  for (int i = e; i < CHL * 38; i += 192) Ds[i / 38][i % 38] = dblp[base38 + i];
  __syncthreads();
  float w6[6], Areg[16], h[16];
  const float* dtwp = dtw + (dir * EC + e) * 6;
  #pragma unroll
  for (int r = 0; r < 6; ++r) w6[r] = dtwp[r];
  float dtbv = dtb[dir * EC + e];
  const float* sf = (const float*)sumb;
  size_t cbase = (size_t)c * SUMW + ((size_t)(dir * 2 + b) * EC + e) * 16;
  #pragma unroll
  for (int n = 0; n < 16; ++n) {
    Areg[n] = -__expf(A_log[(dir * EC + e) * 16 + n]);
    h[n] = sf[2 * (cbase + n)];
  }
  float Dv = Dp[dir * EC + e];
  const float* xg = xc + (size_t)dir * BLEc + (size_t)rbase * EC + e;
  float* yb = ybuf + (size_t)dir * BLEc;
  float x0 = xg[0], x1 = xg[EC];
  for (int s = 0; s < CHL; s += 2) {
    float xn0 = 0.f, xn1 = 0.f;
    if (s + 2 < CHL) { xn0 = xg[(size_t)(s + 2) * EC]; xn1 = xg[(size_t)(s + 3) * EC]; }
    float dtr0 = dtbv, dtr1 = dtbv;
    #pragma unroll
    for (int r = 0; r < 6; ++r) {
      dtr0 = fmaf(Ds[s][r], w6[r], dtr0);
      dtr1 = fmaf(Ds[s + 1][r], w6[r], dtr1);
    }
    float dtv0 = softplusf(dtr0);
    float dtv1 = softplusf(dtr1);
    float dx0 = dtv0 * x0, dx1 = dtv1 * x1;
    float y0 = 0.f, y1 = 0.f;
    #pragma unroll
    for (int n = 0; n < 16; ++n) {
      float a0 = __expf(dtv0 * Areg[n]);
      float a1 = __expf(dtv1 * Areg[n]);
      h[n] = fmaf(h[n], a0, Ds[s][6 + n] * dx0);
      y0 = fmaf(h[n], Ds[s][22 + n], y0);
      h[n] = fmaf(h[n], a1, Ds[s + 1][6 + n] * dx1);
      y1 = fmaf(h[n], Ds[s + 1][22 + n], y1);
    }
    y0 = fmaf(x0, Dv, y0);
    y1 = fmaf(x1, Dv, y1);
    int gs = c * CHL + s;
    int p0 = dir ? (LSEQ - 1 - gs) : gs;
    int p1 = dir ? (LSEQ - 2 - gs) : (gs + 1);
    yb[(size_t)(b * LSEQ + p0) * EC + e] = y0;
    yb[(size_t)(b * LSEQ + p1) * EC + e] = y1;
    x0 = xn0; x1 = xn1;
  }
}

}  // namespace

extern "C" void kernel_launch(void* const* d_in, const int* in_sizes, int n_in,
                              void* d_out, int out_size, void* d_ws, size_t ws_size,
                              hipStream_t stream) {
  const float* x      = (const float*)d_in[0];
  const float* ds_w   = (const float*)d_in[1];
  const float* ds_b   = (const float*)d_in[2];
  const float* ds_ln_w= (const float*)d_in[3];
  const float* ds_ln_b= (const float*)d_in[4];
  const float* ln_w   = (const float*)d_in[5];
  const float* ln_b   = (const float*)d_in[6];
  const float* in_w   = (const float*)d_in[7];
  const float* conv_w = (const float*)d_in[8];
  const float* conv_b = (const float*)d_in[9];
  const float* xp_w   = (const float*)d_in[10];
  const float* dtp_w  = (const float*)d_in[11];
  const float* dtp_b  = (const float*)d_in[12];
  const float* A_log  = (const float*)d_in[13];
  const float* Dp     = (const float*)d_in[14];
  const float* out_w  = (const float*)d_in[15];
  const float* f_ln_w = (const float*)d_in[16];
  const float* f_ln_b = (const float*)d_in[17];
  const float* fc1_w  = (const float*)d_in[18];
  const float* fc1_b  = (const float*)d_in[19];
  const float* fc2_w  = (const float*)d_in[20];
  const float* fc2_b  = (const float*)d_in[21];
  float* outp = (float*)d_out;
  float* ws = (float*)d_ws;

  size_t o = 0;
  float* xf   = ws + o;  o += 1536000;              // residual stream (f32)
  float* xn   = ws + o;  o += 1536000;              // LN out (f32); dblb aliased here
  float* xz   = ws + o;  o += 6144000;              // in-proj / fc1 out (f32)
  float* xcb  = ws + o;  o += 2 * (size_t)BLEc;     // conv out (f32)
  float* ybuf = ws + o;  o += 2 * (size_t)BLEc;     // scan out raw (f32)
  float2* sumb= (float2*)(ws + o); o += 2 * (size_t)NCH * SUMW;  // (P,h)->(carry,h)
  // dblb aliases xn: xn dies at in-proj (before x-proj writes dblb); reborn at
  // the next ln_row, after pass3's last dblb read.
  float* dblb = xn;
  float* xa   = ybuf;   // ds-conv out: dead before pass3 first writes ybuf

  // Stage A: ds-conv as im2col split-bf16 MFMA GEMM (M=16000,N=96,K=384) -> LN.
  gemm_mfma<0, 0, 2><<<dim3(250, 2), 256, 0, stream>>>(
      x, nullptr, nullptr, ds_w, ds_b, xa, MROWS, 96, 384, 96, 0, 0, 0);
  ln_row_kernel<<<4000, 256, 0, stream>>>(xa, ds_ln_w, ds_ln_b, xf, 1e-6f);

  for (int i = 0; i < 2; ++i) {
    ln_row_kernel<<<4000, 256, 0, stream>>>(xf, ln_w + i * 96, ln_b + i * 96, xn, 1e-5f);
    gemm_mfma<0, 0, 0><<<dim3(250, 6), 256, 0, stream>>>(
        xn, nullptr, nullptr, in_w + (size_t)i * 384 * 96, nullptr, xz,
        MROWS, 384, 96, 384, 0, 0, 0);
    conv1d_kernel<<<dim3(6000, 2), 256, 0, stream>>>(
        xz, conv_w + (size_t)i * 2 * EC * 4, conv_b + (size_t)i * 2 * EC, xcb);
    gemm_mfma<0, 0, 0><<<dim3(250, 1, 2), 256, 0, stream>>>(
        xcb, nullptr, nullptr, xp_w + (size_t)i * 2 * 38 * EC, nullptr, dblb,
        MROWS, 38, 192, 38, (size_t)BLEc, (size_t)38 * EC, (size_t)BL38c);
    scan_pass1<<<dim3(NCH, 2, 2), 192, 0, stream>>>(
        xcb, dblb, A_log + (size_t)i * 2 * EC * 16,
        dtp_w + (size_t)i * 2 * EC * 6, dtp_b + (size_t)i * 2 * EC, sumb);
    scan_pass2<<<48, 256, 0, stream>>>(sumb);
    scan_pass3<<<dim3(NCH, 2, 2), 192, 0, stream>>>(
        xcb, dblb, sumb, A_log + (size_t)i * 2 * EC * 16,
        dtp_w + (size_t)i * 2 * EC * 6, dtp_b + (size_t)i * 2 * EC,
        Dp + (size_t)i * 2 * EC, ybuf);
    gemm_mfma<0, 0, 3><<<dim3(250, 2), 256, 0, stream>>>(
        ybuf, ybuf + BLEc, xz, out_w + (size_t)i * 96 * EC, nullptr, xf,
        MROWS, 96, 192, 96, 0, 0, 0);
  }

  ln_row_kernel<<<4000, 256, 0, stream>>>(xf, f_ln_w, f_ln_b, xn, 1e-6f);
  gemm_mfma<1, 0, 0><<<dim3(250, 6), 256, 0, stream>>>(
      xn, nullptr, nullptr, fc1_w, fc1_b, xz, MROWS, 384, 96, 384, 0, 0, 0);
  gemm_mfma<0, 1, 0><<<dim3(250, 2), 256, 0, stream>>>(
      xz, nullptr, nullptr, fc2_w, fc2_b, outp, MROWS, 96, 384, 96, 0, 0, 0);
}

// Round 8
// 390.886 us; speedup vs baseline: 3.5740x; 1.2541x over previous
//
#include <hip/hip_runtime.h>
#include <hip/hip_bf16.h>
#include <math.h>

namespace {

constexpr int LSEQ  = 8000;
constexpr int MROWS = 16000;          // 2 * 8000
constexpr int EC    = 192;
constexpr int NCH   = 400;            // chunks per sequence
constexpr int CHL   = 20;             // chunk length (400*20 = 8000)
constexpr int BLEc  = MROWS * EC;     // 3,072,000
constexpr int BL38c = MROWS * 38;     // 608,000
constexpr int SUMW  = 2 * 2 * EC * 16;  // 12288 scan lanes
constexpr int CT    = 4;              // conv steps per thread

typedef __attribute__((ext_vector_type(8))) short bf16x8;
typedef __attribute__((ext_vector_type(4))) float f32x4;

__device__ __forceinline__ float siluf(float x) { return x / (1.f + __expf(-x)); }
__device__ __forceinline__ float softplusf(float x) {
  if (x > 20.f) return x;
  return __logf(1.f + __expf(x));
}
__device__ __forceinline__ short f2bf(float f) {
  __hip_bfloat16 h = __float2bfloat16(f);
  return *reinterpret_cast<short*>(&h);
}
__device__ __forceinline__ float bf2f(short s) {
  __hip_bfloat16 h;
  *reinterpret_cast<short*>(&h) = s;
  return __bfloat162float(h);
}
// split fp32 -> (hi, lo) bf16 pair: x ~= hi + lo with ~2^-17 representation err
__device__ __forceinline__ void splitbf(float x, short& hi, short& lo) {
  hi = f2bf(x);
  lo = f2bf(x - bf2f(hi));
}

// ---------------- row LN over last dim 96 (wave per row), f32 out ------------
__global__ void ln_row_kernel(const float* __restrict__ in, const float* __restrict__ w,
                              const float* __restrict__ bv, float* __restrict__ out, float eps) {
  int lane = threadIdx.x & 63;
  int row = blockIdx.x * 4 + (threadIdx.x >> 6);   // 4000 blocks * 4 = 16000
  const float* r = in + (size_t)row * 96;
  float v0 = r[lane];
  float v1 = (lane < 32) ? r[64 + lane] : 0.f;
  float s = v0 + v1, s2 = v0 * v0 + v1 * v1;
  #pragma unroll
  for (int o = 32; o; o >>= 1) { s += __shfl_xor(s, o); s2 += __shfl_xor(s2, o); }
  float m = s * (1.f / 96.f);
  float var = s2 * (1.f / 96.f) - m * m;
  float rs = rsqrtf(var + eps);
  float* orow = out + (size_t)row * 96;
  orow[lane] = (v0 - m) * rs * w[lane] + bv[lane];
  if (lane < 32) orow[64 + lane] = (v1 - m) * rs * w[64 + lane] + bv[64 + lane];
}

// ---------------- split-bf16 MFMA GEMM: C[m,n] = act(sum_k A[m,k]W[n,k]+bias) --
// A, W fp32 in memory; staged as (hi,lo) bf16 pairs; 3 MFMAs per fragment pair.
// Tile 64x64, BK=64 (36.9 KB LDS -> 4 blocks/CU), 256 threads (4 waves 2x2).
// AMODE: 0 A fp32 [M][Kk]; 2 im2col from x (2,48,40,40,40);
//        3 (A+A2)*silu(Z[m,192+k]) gated sum (out-proj; Z rows stride 384).
// ACT: 0 none, 1 exact gelu.  OUTM: 0 row-major f32 (ldc); 1 transpose (b,n,l) f32.
template<int ACT, int OUTM, int AMODE>
__global__ __launch_bounds__(256) void gemm_mfma(
    const float* __restrict__ A, const float* __restrict__ A2,
    const float* __restrict__ Zp, const float* __restrict__ W,
    const float* __restrict__ bias, float* __restrict__ Cp,
    int M, int Nn, int Kk, int ldc,
    size_t aStride, size_t wStride, size_t cStride) {
  __shared__ short Al[2][64][72];   // [hi/lo][row][k], row stride 144B
  __shared__ short Bl[2][64][72];
  int tid = threadIdx.x;
  int lane = tid & 63, wid = tid >> 6;
  int wr = wid >> 1, wc = wid & 1;
  int bm = blockIdx.x, bn = blockIdx.y;
  int m0 = bm * 64;
  A += aStride * blockIdx.z;
  if (AMODE == 3) A2 += aStride * blockIdx.z;
  W += wStride * blockIdx.z;
  Cp += cStride * blockIdx.z;
  f32x4 acc[2][2] = {};
  for (int k0 = 0; k0 < Kk; k0 += 64) {
    int Kcur = Kk - k0; if (Kcur > 64) Kcur = 64;
    // ---- stage A ----
    if (AMODE == 2) {
      // col = c*8 + kd*4 + kh*2 + kw; 8 channels per 64-k tile
      #pragma unroll
      for (int i = tid; i < 64 * 32; i += 256) {
        int p = i & 3, c8 = (i >> 2) & 7, r = i >> 5;
        int m = m0 + r;
        int b = m / 8000, l = m % 8000;
        int dd = l / 400, hh = (l / 20) % 20, wd = l % 20;
        int off = (p >> 1) * 1600 + (p & 1) * 40;
        const float* xp = A + ((size_t)b * 48 + (k0 >> 3) + c8) * 64000
                            + dd * 3200 + hh * 80 + wd * 2 + off;
        float2 v = *(const float2*)xp;
        int k = c8 * 8 + p * 2;
        splitbf(v.x, Al[0][r][k], Al[1][r][k]);
        splitbf(v.y, Al[0][r][k + 1], Al[1][r][k + 1]);
      }
    } else {
      #pragma unroll
      for (int i = tid; i < 64 * 8; i += 256) {
        int kq = i & 7, r = i >> 3;
        if (kq * 8 < Kcur) {
          const float* ap = A + (size_t)(m0 + r) * Kk + k0 + kq * 8;
          float4 v0 = *(const float4*)ap;
          float4 v1 = *(const float4*)(ap + 4);
          if (AMODE == 3) {
            const float* bp = A2 + (size_t)(m0 + r) * Kk + k0 + kq * 8;
            float4 u0 = *(const float4*)bp;
            float4 u1 = *(const float4*)(bp + 4);
            const float* zp = Zp + (size_t)(m0 + r) * 384 + 192 + k0 + kq * 8;
            float4 z0 = *(const float4*)zp;
            float4 z1 = *(const float4*)(zp + 4);
            v0.x = (v0.x + u0.x) * siluf(z0.x);
            v0.y = (v0.y + u0.y) * siluf(z0.y);
            v0.z = (v0.z + u0.z) * siluf(z0.z);
            v0.w = (v0.w + u0.w) * siluf(z0.w);
            v1.x = (v1.x + u1.x) * siluf(z1.x);
            v1.y = (v1.y + u1.y) * siluf(z1.y);
            v1.z = (v1.z + u1.z) * siluf(z1.z);
            v1.w = (v1.w + u1.w) * siluf(z1.w);
          }
          float vals[8] = {v0.x, v0.y, v0.z, v0.w, v1.x, v1.y, v1.z, v1.w};
          bf16x8 hi, lo;
          #pragma unroll
          for (int j = 0; j < 8; ++j) { short h, l2; splitbf(vals[j], h, l2); hi[j] = h; lo[j] = l2; }
          *(bf16x8*)&Al[0][r][kq * 8] = hi;
          *(bf16x8*)&Al[1][r][kq * 8] = lo;
        }
      }
    }
    // ---- stage W ----
    #pragma unroll
    for (int i = tid; i < 64 * 8; i += 256) {
      int kq = i & 7, nr = i >> 3;
      if (kq * 8 < Kcur) {
        int n = bn * 64 + nr;
        bf16x8 hi = {0,0,0,0,0,0,0,0}, lo = {0,0,0,0,0,0,0,0};
        if (n < Nn) {
          const float* wp = &W[(size_t)n * Kk + k0 + kq * 8];
          float4 w0 = *(const float4*)wp;
          float4 w1 = *(const float4*)(wp + 4);
          float vals[8] = {w0.x, w0.y, w0.z, w0.w, w1.x, w1.y, w1.z, w1.w};
          #pragma unroll
          for (int j = 0; j < 8; ++j) { short h, l2; splitbf(vals[j], h, l2); hi[j] = h; lo[j] = l2; }
        }
        *(bf16x8*)&Bl[0][nr][kq * 8] = hi;
        *(bf16x8*)&Bl[1][nr][kq * 8] = lo;
      }
    }
    __syncthreads();
    int mr = lane & 15;
    int kq0 = (lane >> 4) * 8;
    #pragma unroll
    for (int ks = 0; ks < 2; ++ks) {
      if (ks * 32 >= Kcur) break;
      int kb = ks * 32 + kq0;
      bf16x8 a0h = *(const bf16x8*)&Al[0][wr * 32 + mr][kb];
      bf16x8 a0l = *(const bf16x8*)&Al[1][wr * 32 + mr][kb];
      bf16x8 a1h = *(const bf16x8*)&Al[0][wr * 32 + 16 + mr][kb];
      bf16x8 a1l = *(const bf16x8*)&Al[1][wr * 32 + 16 + mr][kb];
      bf16x8 b0h = *(const bf16x8*)&Bl[0][wc * 32 + mr][kb];
      bf16x8 b0l = *(const bf16x8*)&Bl[1][wc * 32 + mr][kb];
      bf16x8 b1h = *(const bf16x8*)&Bl[0][wc * 32 + 16 + mr][kb];
      bf16x8 b1l = *(const bf16x8*)&Bl[1][wc * 32 + 16 + mr][kb];
      acc[0][0] = __builtin_amdgcn_mfma_f32_16x16x32_bf16(a0h, b0h, acc[0][0], 0, 0, 0);
      acc[0][0] = __builtin_amdgcn_mfma_f32_16x16x32_bf16(a0h, b0l, acc[0][0], 0, 0, 0);
      acc[0][0] = __builtin_amdgcn_mfma_f32_16x16x32_bf16(a0l, b0h, acc[0][0], 0, 0, 0);
      acc[0][1] = __builtin_amdgcn_mfma_f32_16x16x32_bf16(a0h, b1h, acc[0][1], 0, 0, 0);
      acc[0][1] = __builtin_amdgcn_mfma_f32_16x16x32_bf16(a0h, b1l, acc[0][1], 0, 0, 0);
      acc[0][1] = __builtin_amdgcn_mfma_f32_16x16x32_bf16(a0l, b1h, acc[0][1], 0, 0, 0);
      acc[1][0] = __builtin_amdgcn_mfma_f32_16x16x32_bf16(a1h, b0h, acc[1][0], 0, 0, 0);
      acc[1][0] = __builtin_amdgcn_mfma_f32_16x16x32_bf16(a1h, b0l, acc[1][0], 0, 0, 0);
      acc[1][0] = __builtin_amdgcn_mfma_f32_16x16x32_bf16(a1l, b0h, acc[1][0], 0, 0, 0);
      acc[1][1] = __builtin_amdgcn_mfma_f32_16x16x32_bf16(a1h, b1h, acc[1][1], 0, 0, 0);
      acc[1][1] = __builtin_amdgcn_mfma_f32_16x16x32_bf16(a1h, b1l, acc[1][1], 0, 0, 0);
      acc[1][1] = __builtin_amdgcn_mfma_f32_16x16x32_bf16(a1l, b1h, acc[1][1], 0, 0, 0);
    }
    __syncthreads();
  }
  // ---- epilogue ----
  if (OUTM == 0) {
    #pragma unroll
    for (int fm = 0; fm < 2; ++fm) {
      #pragma unroll
      for (int fn = 0; fn < 2; ++fn) {
        int nn = bn * 64 + wc * 32 + fn * 16 + (lane & 15);
        if (nn >= Nn) continue;
        float bj = bias ? bias[nn] : 0.f;
        #pragma unroll
        for (int r = 0; r < 4; ++r) {
          int mm = m0 + wr * 32 + fm * 16 + (lane >> 4) * 4 + r;
          float v = acc[fm][fn][r] + bj;
          if (ACT == 1) v = 0.5f * v * (1.f + erff(v * 0.70710678118f));
          Cp[(size_t)mm * ldc + nn] = v;
        }
      }
    }
  } else {
    // transpose 64x64 tile via LDS (overlay on Al: 64*65*4 = 16640 <= 18432 B)
    float* Tr = (float*)&Al[0][0][0];
    #pragma unroll
    for (int fm = 0; fm < 2; ++fm)
      #pragma unroll
      for (int fn = 0; fn < 2; ++fn)
        #pragma unroll
        for (int r = 0; r < 4; ++r) {
          int ml = wr * 32 + fm * 16 + (lane >> 4) * 4 + r;
          int nl = wc * 32 + fn * 16 + (lane & 15);
          Tr[ml * 65 + nl] = acc[fm][fn][r];
        }
    __syncthreads();
    int n = tid & 63, q = tid >> 6;
    int nn = bn * 64 + n;
    if (nn < Nn) {
      float bj = bias ? bias[nn] : 0.f;
      int b = m0 / LSEQ;
      int l0 = m0 % LSEQ + q * 16;
      float* outc = Cp + ((size_t)(b * 96 + nn)) * LSEQ + l0;
      #pragma unroll
      for (int j = 0; j < 16; j += 4) {
        float4 v;
        v.x = Tr[(q * 16 + j    ) * 65 + n] + bj;
        v.y = Tr[(q * 16 + j + 1) * 65 + n] + bj;
        v.z = Tr[(q * 16 + j + 2) * 65 + n] + bj;
        v.w = Tr[(q * 16 + j + 3) * 65 + n] + bj;
        *(float4*)&outc[j] = v;
      }
    }
  }
}

// ---------------- causal depthwise conv1d (K=4) + silu, BOTH dirs fused ------
// Thread: (b, s-block of CT steps, e4 of 4 channels). One 10-row float4 window
// serves dir0 outputs s0..s0+CT-1 and dir1 outputs stored at the same rows
// (dir1 value at reversed pos s' = L-1-s uses original rows s..s+3).
__global__ void conv1d_kernel(const float* __restrict__ xz, const float* __restrict__ cw,
                              const float* __restrict__ cb, float* __restrict__ xc) {
  int idx = blockIdx.x * 256 + threadIdx.x;   // 2 * (8000/CT) * 48 = 192,000
  int e4 = idx % 48;
  int t  = idx / 48;
  int sblk = t % (LSEQ / CT);
  int b    = t / (LSEQ / CT);
  int e = e4 * 4;
  int s0 = sblk * CT;
  const float* base = xz + ((size_t)b * LSEQ) * 384 + e;
  float4 wnd[CT + 6];
  #pragma unroll
  for (int j = 0; j < CT + 6; ++j) {
    int r = s0 - 3 + j;
    if (r >= 0 && r < LSEQ) wnd[j] = *(const float4*)&base[(size_t)r * 384];
    else wnd[j] = make_float4(0.f, 0.f, 0.f, 0.f);
  }
  float W0[4][4], W1[4][4], CB0[4], CB1[4];
  #pragma unroll
  for (int i2 = 0; i2 < 4; ++i2) {
    float4 q0 = *(const float4*)&cw[(e + i2) * 4];
    float4 q1 = *(const float4*)&cw[EC * 4 + (e + i2) * 4];
    W0[i2][0] = q0.x; W0[i2][1] = q0.y; W0[i2][2] = q0.z; W0[i2][3] = q0.w;
    W1[i2][0] = q1.x; W1[i2][1] = q1.y; W1[i2][2] = q1.z; W1[i2][3] = q1.w;
    CB0[i2] = cb[e + i2];
    CB1[i2] = cb[EC + e + i2];
  }
  float* out0 = xc + ((size_t)b * LSEQ) * EC + e;
  float* out1 = xc + (size_t)BLEc + ((size_t)b * LSEQ) * EC + e;
  #pragma unroll
  for (int j = 0; j < CT; ++j) {
    float o0[4], o1[4];
    #pragma unroll
    for (int i2 = 0; i2 < 4; ++i2) { o0[i2] = CB0[i2]; o1[i2] = CB1[i2]; }
    #pragma unroll
    for (int k = 0; k < 4; ++k) {
      float4 v0 = wnd[j + k];          // original row s0+j-3+k  (dir0 tap k)
      float4 v1 = wnd[j + 6 - k];      // original row s0+j+3-k  (dir1 tap k)
      const float* v0p = (const float*)&v0;
      const float* v1p = (const float*)&v1;
      #pragma unroll
      for (int i2 = 0; i2 < 4; ++i2) {
        o0[i2] = fmaf(W0[i2][k], v0p[i2], o0[i2]);
        o1[i2] = fmaf(W1[i2][k], v1p[i2], o1[i2]);
      }
    }
    float4 r0 = make_float4(siluf(o0[0]), siluf(o0[1]), siluf(o0[2]), siluf(o0[3]));
    float4 r1 = make_float4(siluf(o1[0]), siluf(o1[1]), siluf(o1[2]), siluf(o1[3]));
    *(float4*)&out0[(size_t)(s0 + j) * EC] = r0;
    *(float4*)&out1[(size_t)(LSEQ - 1 - (s0 + j)) * EC] = r1;
  }
}

// ---------------- chunked selective scan, e-parallel, dt fused ---------------
__global__ void scan_pass1(const float* __restrict__ xc, const float* __restrict__ dbl,
                           const float* __restrict__ A_log, const float* __restrict__ dtw,
                           const float* __restrict__ dtb, float2* __restrict__ sumb) {
  int c = blockIdx.x, b = blockIdx.y, dir = blockIdx.z;
  int e = threadIdx.x;    // 192
  __shared__ float Ds[CHL][40];
  const float* dblp = dbl + (size_t)dir * BL38c;
  int rbase = b * LSEQ + c * CHL;
  size_t base38 = (size_t)rbase * 38;
  for (int i = e; i < CHL * 38; i += 192) Ds[i / 38][i % 38] = dblp[base38 + i];
  __syncthreads();
  float w6[6], Areg[16], h[16], P[16];
  const float* dtwp = dtw + (dir * EC + e) * 6;
  #pragma unroll
  for (int r = 0; r < 6; ++r) w6[r] = dtwp[r];
  float dtbv = dtb[dir * EC + e];
  #pragma unroll
  for (int n = 0; n < 16; ++n) {
    Areg[n] = -__expf(A_log[(dir * EC + e) * 16 + n]);
    h[n] = 0.f; P[n] = 1.f;
  }
  const float* xg = xc + (size_t)dir * BLEc + (size_t)rbase * EC + e;
  float x0 = xg[0], x1 = xg[EC];
  for (int s = 0; s < CHL; s += 2) {
    float xn0 = 0.f, xn1 = 0.f;
    if (s + 2 < CHL) { xn0 = xg[(size_t)(s + 2) * EC]; xn1 = xg[(size_t)(s + 3) * EC]; }
    float dtr0 = dtbv, dtr1 = dtbv;
    #pragma unroll
    for (int r = 0; r < 6; ++r) {
      dtr0 = fmaf(Ds[s][r], w6[r], dtr0);
      dtr1 = fmaf(Ds[s + 1][r], w6[r], dtr1);
    }
    float dtv0 = softplusf(dtr0);
    float dtv1 = softplusf(dtr1);
    float dx0 = dtv0 * x0, dx1 = dtv1 * x1;
    #pragma unroll
    for (int n = 0; n < 16; ++n) {
      float a0 = __expf(dtv0 * Areg[n]);
      float a1 = __expf(dtv1 * Areg[n]);
      h[n] = fmaf(h[n], a0, Ds[s][6 + n] * dx0);
      h[n] = fmaf(h[n], a1, Ds[s + 1][6 + n] * dx1);
      P[n] *= a0 * a1;
    }
    x0 = xn0; x1 = xn1;
  }
  size_t sbase = (size_t)c * SUMW + ((size_t)(dir * 2 + b) * EC + e) * 16;
  #pragma unroll
  for (int n = 0; n < 16; ++n) sumb[sbase + n] = make_float2(P[n], h[n]);
}

// pass2: thread per scan-lane; batch-25 loads to hide latency; carry written
// in-place over the .x slot of sumb.
__global__ void scan_pass2(float2* __restrict__ sumb) {
  int idx = blockIdx.x * 256 + threadIdx.x;   // SUMW
  if (idx >= SUMW) return;
  float* sf = (float*)sumb;
  float H = 0.f;
  for (int c0 = 0; c0 < NCH; c0 += 25) {
    float2 pv[25];
    #pragma unroll
    for (int j = 0; j < 25; ++j) pv[j] = sumb[(size_t)(c0 + j) * SUMW + idx];
    #pragma unroll
    for (int j = 0; j < 25; ++j) {
      sf[2 * ((size_t)(c0 + j) * SUMW + idx)] = H;
      H = fmaf(H, pv[j].x, pv[j].y);
    }
  }
}

// pass3: recompute with carry-in; y = sum_n C*h + xc*D (NO gate), un-reverse.
__global__ void scan_pass3(const float* __restrict__ xc, const float* __restrict__ dbl,
                           const float2* __restrict__ sumb, const float* __restrict__ A_log,
                           const float* __restrict__ dtw, const float* __restrict__ dtb,
                           const float* __restrict__ Dp, float* __restrict__ ybuf) {
  int c = blockIdx.x, b = blockIdx.y, dir = blockIdx.z;
  int e = threadIdx.x;    // 192
  __shared__ float Ds[CHL][40];
  const float* dblp = dbl + (size_t)dir * BL38c;
  int rbase = b * LSEQ + c * CHL;
  size_t base38 = (size_t)rbase * 38;
  for (int i = e; i < CHL * 38; i += 192) Ds[i / 38][i % 38] = dblp[base38 + i];
  __syncthreads();
  float w6[6], Areg[16], h[16];
  const float* dtwp = dtw + (dir * EC + e) * 6;
  #pragma unroll
  for (int r = 0; r < 6; ++r) w6[r] = dtwp[r];
  float dtbv = dtb[dir * EC + e];
  const float* sf = (const float*)sumb;
  size_t cbase = (size_t)c * SUMW + ((size_t)(dir * 2 + b) * EC + e) * 16;
  #pragma unroll
  for (int n = 0; n < 16; ++n) {
    Areg[n] = -__expf(A_log[(dir * EC + e) * 16 + n]);
    h[n] = sf[2 * (cbase + n)];
  }
  float Dv = Dp[dir * EC + e];
  const float* xg = xc + (size_t)dir * BLEc + (size_t)rbase * EC + e;
  float* yb = ybuf + (size_t)dir * BLEc;
  float x0 = xg[0], x1 = xg[EC];
  for (int s = 0; s < CHL; s += 2) {
    float xn0 = 0.f, xn1 = 0.f;
    if (s + 2 < CHL) { xn0 = xg[(size_t)(s + 2) * EC]; xn1 = xg[(size_t)(s + 3) * EC]; }
    float dtr0 = dtbv, dtr1 = dtbv;
    #pragma unroll
    for (int r = 0; r < 6; ++r) {
      dtr0 = fmaf(Ds[s][r], w6[r], dtr0);
      dtr1 = fmaf(Ds[s + 1][r], w6[r], dtr1);
    }
    float dtv0 = softplusf(dtr0);
    float dtv1 = softplusf(dtr1);
    float dx0 = dtv0 * x0, dx1 = dtv1 * x1;
    float y0 = 0.f, y1 = 0.f;
    #pragma unroll
    for (int n = 0; n < 16; ++n) {
      float a0 = __expf(dtv0 * Areg[n]);
      float a1 = __expf(dtv1 * Areg[n]);
      h[n] = fmaf(h[n], a0, Ds[s][6 + n] * dx0);
      y0 = fmaf(h[n], Ds[s][22 + n], y0);
      h[n] = fmaf(h[n], a1, Ds[s + 1][6 + n] * dx1);
      y1 = fmaf(h[n], Ds[s + 1][22 + n], y1);
    }
    y0 = fmaf(x0, Dv, y0);
    y1 = fmaf(x1, Dv, y1);
    int gs = c * CHL + s;
    int p0 = dir ? (LSEQ - 1 - gs) : gs;
    int p1 = dir ? (LSEQ - 2 - gs) : (gs + 1);
    yb[(size_t)(b * LSEQ + p0) * EC + e] = y0;
    yb[(size_t)(b * LSEQ + p1) * EC + e] = y1;
    x0 = xn0; x1 = xn1;
  }
}

}  // namespace

extern "C" void kernel_launch(void* const* d_in, const int* in_sizes, int n_in,
                              void* d_out, int out_size, void* d_ws, size_t ws_size,
                              hipStream_t stream) {
  const float* x      = (const float*)d_in[0];
  const float* ds_w   = (const float*)d_in[1];
  const float* ds_b   = (const float*)d_in[2];
  const float* ds_ln_w= (const float*)d_in[3];
  const float* ds_ln_b= (const float*)d_in[4];
  const float* ln_w   = (const float*)d_in[5];
  const float* ln_b   = (const float*)d_in[6];
  const float* in_w   = (const float*)d_in[7];
  const float* conv_w = (const float*)d_in[8];
  const float* conv_b = (const float*)d_in[9];
  const float* xp_w   = (const float*)d_in[10];
  const float* dtp_w  = (const float*)d_in[11];
  const float* dtp_b  = (const float*)d_in[12];
  const float* A_log  = (const float*)d_in[13];
  const float* Dp     = (const float*)d_in[14];
  const float* out_w  = (const float*)d_in[15];
  const float* f_ln_w = (const float*)d_in[16];
  const float* f_ln_b = (const float*)d_in[17];
  const float* fc1_w  = (const float*)d_in[18];
  const float* fc1_b  = (const float*)d_in[19];
  const float* fc2_w  = (const float*)d_in[20];
  const float* fc2_b  = (const float*)d_in[21];
  float* outp = (float*)d_out;
  float* ws = (float*)d_ws;

  size_t o = 0;
  float* xf   = ws + o;  o += 1536000;              // residual stream (f32)
  float* xn   = ws + o;  o += 1536000;              // LN out (f32); dblb aliased here
  float* xz   = ws + o;  o += 6144000;              // in-proj / fc1 out (f32)
  float* xcb  = ws + o;  o += 2 * (size_t)BLEc;     // conv out (f32)
  float* ybuf = ws + o;  o += 2 * (size_t)BLEc;     // scan out raw (f32)
  float2* sumb= (float2*)(ws + o); o += 2 * (size_t)NCH * SUMW;  // (P,h)->(carry,h)
  // dblb aliases xn: xn dies at in-proj (before x-proj writes dblb); reborn at
  // the next ln_row, after pass3's last dblb read.
  float* dblb = xn;
  float* xa   = ybuf;   // ds-conv out: dead before pass3 first writes ybuf

  // Stage A: ds-conv as im2col split-bf16 MFMA GEMM (M=16000,N=96,K=384) -> LN.
  gemm_mfma<0, 0, 2><<<dim3(250, 2), 256, 0, stream>>>(
      x, nullptr, nullptr, ds_w, ds_b, xa, MROWS, 96, 384, 96, 0, 0, 0);
  ln_row_kernel<<<4000, 256, 0, stream>>>(xa, ds_ln_w, ds_ln_b, xf, 1e-6f);

  for (int i = 0; i < 2; ++i) {
    ln_row_kernel<<<4000, 256, 0, stream>>>(xf, ln_w + i * 96, ln_b + i * 96, xn, 1e-5f);
    gemm_mfma<0, 0, 0><<<dim3(250, 6), 256, 0, stream>>>(
        xn, nullptr, nullptr, in_w + (size_t)i * 384 * 96, nullptr, xz,
        MROWS, 384, 96, 384, 0, 0, 0);
    conv1d_kernel<<<750, 256, 0, stream>>>(
        xz, conv_w + (size_t)i * 2 * EC * 4, conv_b + (size_t)i * 2 * EC, xcb);
    gemm_mfma<0, 0, 0><<<dim3(250, 1, 2), 256, 0, stream>>>(
        xcb, nullptr, nullptr, xp_w + (size_t)i * 2 * 38 * EC, nullptr, dblb,
        MROWS, 38, 192, 38, (size_t)BLEc, (size_t)38 * EC, (size_t)BL38c);
    scan_pass1<<<dim3(NCH, 2, 2), 192, 0, stream>>>(
        xcb, dblb, A_log + (size_t)i * 2 * EC * 16,
        dtp_w + (size_t)i * 2 * EC * 6, dtp_b + (size_t)i * 2 * EC, sumb);
    scan_pass2<<<48, 256, 0, stream>>>(sumb);
    scan_pass3<<<dim3(NCH, 2, 2), 192, 0, stream>>>(
        xcb, dblb, sumb, A_log + (size_t)i * 2 * EC * 16,
        dtp_w + (size_t)i * 2 * EC * 6, dtp_b + (size_t)i * 2 * EC,
        Dp + (size_t)i * 2 * EC, ybuf);
    gemm_mfma<0, 0, 3><<<dim3(250, 2), 256, 0, stream>>>(
        ybuf, ybuf + BLEc, xz, out_w + (size_t)i * 96 * EC, nullptr, xf,
        MROWS, 96, 192, 96, 0, 0, 0);
  }

  ln_row_kernel<<<4000, 256, 0, stream>>>(xf, f_ln_w, f_ln_b, xn, 1e-6f);
  gemm_mfma<1, 0, 0><<<dim3(250, 6), 256, 0, stream>>>(
      xn, nullptr, nullptr, fc1_w, fc1_b, xz, MROWS, 384, 96, 384, 0, 0, 0);
  gemm_mfma<0, 1, 0><<<dim3(250, 2), 256, 0, stream>>>(
      xz, nullptr, nullptr, fc2_w, fc2_b, outp, MROWS, 96, 384, 96, 0, 0, 0);
}